// Round 5
// baseline (421.384 us; speedup 1.0000x reference)
//
#include <hip/hip_runtime.h>
#include <hip/hip_bf16.h>

#define NN 40000
#define NE 640000
#define NG 2048
#define DD 128
#define NT 10
#define NL 5
#define NB 80  // dst buckets of 512 nodes

typedef __attribute__((ext_vector_type(8))) short short8;
typedef __attribute__((ext_vector_type(4))) float f32x4;
typedef unsigned short ushort_t;

static __device__ __forceinline__ ushort_t f2b(float f) {
    return __bfloat16_as_ushort(__float2bfloat16(f));
}
static __device__ __forceinline__ float b2f(ushort_t u) {
    return __bfloat162float(__ushort_as_bfloat16(u));
}

// ---------------- fused setup: tables + atom-encode + degree histogram -----
__global__ void __launch_bounds__(256)
k_setup(const float* __restrict__ W1, const float* __restrict__ W2,
        const float* __restrict__ bemb, const int* __restrict__ xa,
        const float* __restrict__ aemb, const int* __restrict__ ei,
        ushort_t* __restrict__ W1P, ushort_t* __restrict__ W2P,
        ushort_t* __restrict__ ebsum16, ushort_t* __restrict__ x16,
        int* __restrict__ deg) {
    int b = blockIdx.x, t = threadIdx.x;
    if (b < 1280) {
        int tid = b * 256 + t;  // < NL*65536
        int layer = tid >> 16;
        int r = tid & 65535;
        int half = r >> 15;
        int q = r & 32767;
        int j = q & 7;
        int lane = (q >> 3) & 63;
        if (half == 0) {
            int kk = (q >> 9) & 3;
            int nt = q >> 11;
            int n = nt * 16 + (lane & 15);
            int k = kk * 32 + (lane >> 4) * 8 + j;
            W1P[layer * 32768 + q] = f2b(W1[(layer * DD + k) * 256 + n]);
        } else {
            int kk = (q >> 9) & 7;
            int nt = q >> 12;
            int n = nt * 16 + (lane & 15);
            int k = kk * 32 + (lane >> 4) * 8 + j;
            W2P[layer * 32768 + q] = f2b(W2[(layer * 256 + k) * DD + n]);
        }
        int d = tid & 127;
        int c = (tid >> 7) & 511;
        const float* bl = bemb + (size_t)layer * 3 * 8 * DD;
        ebsum16[tid] = f2b(bl[(c & 7) * DD + d] + bl[(8 + ((c >> 3) & 7)) * DD + d] +
                           bl[(16 + (c >> 6)) * DD + d]);
    } else if (b < 21280) {
        int half = t >> 7, d = t & 127;
        int n = (b - 1280) * 2 + half;
        __shared__ int idx[2][9];
        if (d < 9) idx[half][d] = xa[n * 9 + d];
        __syncthreads();
        float s = 0.f;
#pragma unroll
        for (int f = 0; f < 9; ++f) s += aemb[(f * 64 + idx[half][f]) * DD + d];
        x16[n * DD + d] = f2b(s);
    } else {
        int e = (b - 21280) * 256 + t;
        atomicAdd(&deg[ei[NE + e]], 1);
    }
}

// ---------------- CSR build -----------------------------------------------

__global__ void k_scan1(const int* __restrict__ deg, int* __restrict__ off,
                        int* __restrict__ blksum) {
    int b = blockIdx.x, t = threadIdx.x;
    int i = b * 256 + t;
    __shared__ int s[256];
    int v = (i < NN) ? deg[i] : 0;
    s[t] = v;
    __syncthreads();
    for (int d = 1; d < 256; d <<= 1) {
        int add = (t >= d) ? s[t - d] : 0;
        __syncthreads();
        s[t] += add;
        __syncthreads();
    }
    if (i <= NN) off[i] = s[t] - v;
    if (t == 255) blksum[b] = s[255];
}

__global__ void k_scan2(int* __restrict__ blk) {
    int t = threadIdx.x;
    __shared__ int s[256];
    int v = blk[t];
    s[t] = v;
    __syncthreads();
    for (int d = 1; d < 256; d <<= 1) {
        int add = (t >= d) ? s[t - d] : 0;
        __syncthreads();
        s[t] += add;
        __syncthreads();
    }
    blk[256 + t] = s[t] - v;  // exclusive
}

__global__ void k_scan3(int* __restrict__ off, const int* __restrict__ blk) {
    int b = blockIdx.x, t = threadIdx.x;
    int i = b * 256 + t;
    if (i <= NN) off[i] += blk[256 + b];
}

// Phase A: bin edges by dst bucket into dense runs of ebuf.
__global__ void __launch_bounds__(256)
k_bucket(const int* __restrict__ ei, const int* __restrict__ ea,
         const int* __restrict__ off, int* __restrict__ gbk,
         int2* __restrict__ ebuf) {
    __shared__ int hist[NB];
    __shared__ int sbase[NB];
    int t = threadIdx.x;
    int e0 = blockIdx.x * 1024;
    if (t < NB) hist[t] = 0;
    __syncthreads();
    int rank[4], buck[4], rec[4], dstv[4];
#pragma unroll
    for (int k = 0; k < 4; ++k) {
        int e = e0 + k * 256 + t;
        int src = ei[e];
        int dst = ei[NE + e];
        int a0 = ea[e * 3 + 0], a1 = ea[e * 3 + 1], a2 = ea[e * 3 + 2];
        rec[k] = src | ((a0 | (a1 << 3) | (a2 << 6)) << 16);
        dstv[k] = dst;
        int b = dst >> 9;
        buck[k] = b;
        rank[k] = atomicAdd(&hist[b], 1);
    }
    __syncthreads();
    if (t < NB) sbase[t] = atomicAdd(&gbk[t], hist[t]);
    __syncthreads();
#pragma unroll
    for (int k = 0; k < 4; ++k) {
        int b = buck[k];
        int slot = off[b << 9] + sbase[b] + rank[k];
        ebuf[slot] = make_int2(rec[k], dstv[k]);
    }
}

// Phase B: scatter within L2-resident bucket windows. epack stays PACKED
// (src | code<<16) as a single int -> half the stream and half the index
// registers in the gather.
__global__ void k_scatter2(const int2* __restrict__ ebuf, const int* __restrict__ off,
                           int* __restrict__ cursor, int* __restrict__ epack) {
    int i = blockIdx.x * 256 + threadIdx.x;
    int2 s = ebuf[i];
    int dst = s.y;
    int p = off[dst] + atomicAdd(&cursor[dst], 1);
    epack[p] = s.x;
}

// Gather: wave per node, lane handles 2 dims (ushort2). 4 nodes/block.
// 8-deep pipelined edge loop (round-3 structure) with packed int records:
// e[8]+f[8] = 16 VGPR (was 32) -> fits under the 64-VGPR cliff; 8 blocks/CU
// pinned -> 32 waves/CU for 2x latency hiding.
__global__ void __launch_bounds__(256, 8)
k_gather(const ushort_t* __restrict__ xin, const int* __restrict__ off,
         const int* __restrict__ epack, const ushort_t* __restrict__ ebsum16,
         const float* __restrict__ eps, int layer, ushort_t* __restrict__ h16) {
    int t = threadIdx.x;
    int lane = t & 63;
    int n = blockIdx.x * 4 + (t >> 6);
    const ushort2* x2 = (const ushort2*)xin;
    const ushort2* eb2 = (const ushort2*)ebsum16;
    ushort2 xv = x2[n * 64 + lane];
    float es = 1.f + eps[layer];
    float ax = es * b2f(xv.x), ay = es * b2f(xv.y);
    int p = off[n], p1 = off[n + 1];

    int e[8], f[8];
    bool have = (p + 8 <= p1);
    if (have) {
#pragma unroll
        for (int k = 0; k < 8; ++k) e[k] = epack[p + k];
    }
    while (have) {
        int np = p + 8;
        bool nh = (np + 8 <= p1);
        if (nh) {
#pragma unroll
            for (int k = 0; k < 8; ++k) f[k] = epack[np + k];
        }
        ushort2 vv[8], ss[8];
#pragma unroll
        for (int k = 0; k < 8; ++k) {
            vv[k] = eb2[(e[k] >> 16) * 64 + lane];
            ss[k] = x2[(e[k] & 0xFFFF) * 64 + lane];
        }
#pragma unroll
        for (int k = 0; k < 8; ++k) {
            ax += fmaxf(b2f(vv[k].x) + b2f(ss[k].x), 0.f);
            ay += fmaxf(b2f(vv[k].y) + b2f(ss[k].y), 0.f);
        }
        p = np;
#pragma unroll
        for (int k = 0; k < 8; ++k) e[k] = f[k];
        have = nh;
    }
    if (p + 4 <= p1) {
        int e4[4];
#pragma unroll
        for (int k = 0; k < 4; ++k) e4[k] = epack[p + k];
        ushort2 vv[4], ss[4];
#pragma unroll
        for (int k = 0; k < 4; ++k) {
            vv[k] = eb2[(e4[k] >> 16) * 64 + lane];
            ss[k] = x2[(e4[k] & 0xFFFF) * 64 + lane];
        }
#pragma unroll
        for (int k = 0; k < 4; ++k) {
            ax += fmaxf(b2f(vv[k].x) + b2f(ss[k].x), 0.f);
            ay += fmaxf(b2f(vv[k].y) + b2f(ss[k].y), 0.f);
        }
        p += 4;
    }
    for (; p < p1; ++p) {
        int er = epack[p];
        ushort2 ev = eb2[(er >> 16) * 64 + lane];
        ushort2 sv = x2[(er & 0xFFFF) * 64 + lane];
        ax += fmaxf(b2f(ev.x) + b2f(sv.x), 0.f);
        ay += fmaxf(b2f(ev.y) + b2f(sv.y), 0.f);
    }
    ushort2 o;
    o.x = f2b(ax);
    o.y = f2b(ay);
    ((ushort2*)h16)[n * 64 + lane] = o;
}

// Fused MLP on MFMA: 64 nodes per block (was 32) -> weight stream per row
// halved (128KB per 64 rows), 2x MFMA per B-frag load. 256 threads, 4 waves.
__global__ void __launch_bounds__(256)
k_mlp_mfma(const ushort_t* __restrict__ h16, const ushort_t* __restrict__ W1P,
           const ushort_t* __restrict__ W2P, const float* __restrict__ b1,
           const float* __restrict__ g1, const float* __restrict__ bt1,
           const float* __restrict__ m1, const float* __restrict__ v1,
           const float* __restrict__ b2_, const float* __restrict__ gO,
           const float* __restrict__ btO, const float* __restrict__ mO,
           const float* __restrict__ vO, int relu, ushort_t* __restrict__ xout) {
    __shared__ ushort_t aS[64 * 136];   // 64 rows x 128 (pad +8) = 17.4 KB
    __shared__ ushort_t mid[64 * 264];  // 64 rows x 256 (pad +8) = 33.8 KB
    int t = threadIdx.x;
    int wave = t >> 6, lane = t & 63;
    int row0 = blockIdx.x * 64;
    int lrow = lane & 15, quad = lane >> 4;

#pragma unroll
    for (int ps = 0; ps < 4; ++ps) {
        int idx = ps * 256 + t;
        int r = idx >> 4, c = (idx & 15) * 8;
        *(short8*)&aS[r * 136 + c] = *(const short8*)&h16[(row0 + r) * DD + c];
    }
    __syncthreads();

    f32x4 acc1[4][4];
#pragma unroll
    for (int rt = 0; rt < 4; ++rt)
#pragma unroll
        for (int i = 0; i < 4; ++i) acc1[rt][i] = (f32x4){0.f, 0.f, 0.f, 0.f};
#pragma unroll
    for (int kk = 0; kk < 4; ++kk) {
        short8 af[4];
#pragma unroll
        for (int rt = 0; rt < 4; ++rt)
            af[rt] = *(const short8*)&aS[(rt * 16 + lrow) * 136 + kk * 32 + quad * 8];
#pragma unroll
        for (int i = 0; i < 4; ++i) {
            int nt = wave * 4 + i;
            short8 bf = *(const short8*)&W1P[((nt * 4 + kk) * 64 + lane) * 8];
#pragma unroll
            for (int rt = 0; rt < 4; ++rt)
                acc1[rt][i] = __builtin_amdgcn_mfma_f32_16x16x32_bf16(af[rt], bf, acc1[rt][i], 0, 0, 0);
        }
    }
#pragma unroll
    for (int i = 0; i < 4; ++i) {
        int col = (wave * 4 + i) * 16 + lrow;
        float s1 = g1[col] * rsqrtf(v1[col] + 1e-5f);
        float sh = bt1[col] - (m1[col] - b1[col]) * s1;
#pragma unroll
        for (int rt = 0; rt < 4; ++rt)
#pragma unroll
            for (int r = 0; r < 4; ++r) {
                int row = rt * 16 + quad * 4 + r;
                float o = acc1[rt][i][r] * s1 + sh;
                mid[row * 264 + col] = f2b(fmaxf(o, 0.f));
            }
    }
    __syncthreads();

    f32x4 acc2[4][2];
#pragma unroll
    for (int rt = 0; rt < 4; ++rt)
#pragma unroll
        for (int i = 0; i < 2; ++i) acc2[rt][i] = (f32x4){0.f, 0.f, 0.f, 0.f};
#pragma unroll
    for (int kk = 0; kk < 8; ++kk) {
        short8 af[4];
#pragma unroll
        for (int rt = 0; rt < 4; ++rt)
            af[rt] = *(const short8*)&mid[(rt * 16 + lrow) * 264 + kk * 32 + quad * 8];
#pragma unroll
        for (int i = 0; i < 2; ++i) {
            int nt = wave * 2 + i;
            short8 bf = *(const short8*)&W2P[((nt * 8 + kk) * 64 + lane) * 8];
#pragma unroll
            for (int rt = 0; rt < 4; ++rt)
                acc2[rt][i] = __builtin_amdgcn_mfma_f32_16x16x32_bf16(af[rt], bf, acc2[rt][i], 0, 0, 0);
        }
    }
#pragma unroll
    for (int i = 0; i < 2; ++i) {
        int col = (wave * 2 + i) * 16 + lrow;
        float s = gO[col] * rsqrtf(vO[col] + 1e-5f);
        float sh = btO[col] - (mO[col] - b2_[col]) * s;
#pragma unroll
        for (int rt = 0; rt < 4; ++rt)
#pragma unroll
            for (int r = 0; r < 4; ++r) {
                int row = rt * 16 + quad * 4 + r;
                float o = acc2[rt][i][r] * s + sh;
                if (relu) o = fmaxf(o, 0.f);
                xout[(row0 + row) * DD + col] = f2b(o);
            }
    }
}

// Fused pool+head: block g reduces its node range, then computes out[g].
__global__ void k_poolhead(const ushort_t* __restrict__ x16,
                           const int* __restrict__ batch,
                           const float* __restrict__ Wp, const float* __restrict__ bp,
                           float* __restrict__ out) {
    int g = blockIdx.x, d = threadIdx.x;  // 128 threads
    int lo = 0, hi = NN;
    while (lo < hi) { int m = (lo + hi) >> 1; if (batch[m] < g) lo = m + 1; else hi = m; }
    int start = lo;
    hi = NN;
    while (lo < hi) { int m = (lo + hi) >> 1; if (batch[m] < g + 1) lo = m + 1; else hi = m; }
    int end = lo;
    float s = 0.f;
    for (int n = start; n < end; ++n) s += b2f(x16[n * DD + d]);
    float c = fmaxf((float)(end - start), 1.f);
    __shared__ float p[DD];
    p[d] = s / c;
    __syncthreads();
    if (d < NT) {
        float acc = bp[d];
#pragma unroll 8
        for (int k = 0; k < DD; ++k) acc = fmaf(p[k], Wp[k * NT + d], acc);
        out[g * NT + d] = acc;
    }
}

extern "C" void kernel_launch(void* const* d_in, const int* in_sizes, int n_in,
                              void* d_out, int out_size, void* d_ws, size_t ws_size,
                              hipStream_t stream) {
    const int* x_atom = (const int*)d_in[0];
    const int* edge_index = (const int*)d_in[1];
    const int* edge_attr = (const int*)d_in[2];
    const int* batch = (const int*)d_in[3];
    const float* atom_emb = (const float*)d_in[4];
    const float* bond_emb = (const float*)d_in[5];
    const float* eps = (const float*)d_in[6];
    const float* W1 = (const float*)d_in[7];
    const float* b1 = (const float*)d_in[8];
    const float* g1 = (const float*)d_in[9];
    const float* bt1 = (const float*)d_in[10];
    const float* m1 = (const float*)d_in[11];
    const float* v1 = (const float*)d_in[12];
    const float* W2 = (const float*)d_in[13];
    const float* b2 = (const float*)d_in[14];
    const float* gO = (const float*)d_in[15];
    const float* btO = (const float*)d_in[16];
    const float* mO = (const float*)d_in[17];
    const float* vO = (const float*)d_in[18];
    const float* Wp = (const float*)d_in[19];
    const float* bp = (const float*)d_in[20];

    ushort_t* x16a = (ushort_t*)d_ws;        // N*D bf16
    ushort_t* x16b = x16a + NN * DD;         // N*D bf16
    ushort_t* h16 = x16b + NN * DD;          // N*D bf16
    ushort_t* W1P = h16 + NN * DD;           // NL*32768 bf16
    ushort_t* W2P = W1P + NL * 32768;        // NL*32768 bf16
    ushort_t* ebsum16 = W2P + NL * 32768;    // NL*512*128 bf16
    int* deg = (int*)(ebsum16 + NL * 65536); // 40000
    int* off = deg + NN;                     // 40064
    int* blk = off + 40064;                  // 512
    int* cursor = blk + 512;                 // 40000
    int* gbk = cursor + NN;                  // 128
    int* epack = gbk + 128;                  // NE int (packed src|code<<16)
    int2* ebuf = (int2*)(epack + NE);        // NE int2

    hipMemsetAsync(deg, 0, (NN + 40064 + 512 + NN + 128) * sizeof(int), stream);

    k_setup<<<23780, 256, 0, stream>>>(W1, W2, bond_emb, x_atom, atom_emb,
                                       edge_index, W1P, W2P, ebsum16, x16a, deg);
    k_scan1<<<157, 256, 0, stream>>>(deg, off, blk);
    k_scan2<<<1, 256, 0, stream>>>(blk);
    k_scan3<<<157, 256, 0, stream>>>(off, blk);
    k_bucket<<<NE / 1024, 256, 0, stream>>>(edge_index, edge_attr, off, gbk, ebuf);
    k_scatter2<<<NE / 256, 256, 0, stream>>>(ebuf, off, cursor, epack);

    for (int i = 0; i < NL; ++i) {
        ushort_t* xin = (i & 1) ? x16b : x16a;
        ushort_t* xout = (i & 1) ? x16a : x16b;
        k_gather<<<NN / 4, 256, 0, stream>>>(xin, off, epack, ebsum16 + i * 65536,
                                             eps, i, h16);
        k_mlp_mfma<<<NN / 64, 256, 0, stream>>>(
            h16, W1P + (size_t)i * 32768, W2P + (size_t)i * 32768, b1 + i * 256,
            g1 + i * 256, bt1 + i * 256, m1 + i * 256, v1 + i * 256, b2 + i * DD,
            gO + i * DD, btO + i * DD, mO + i * DD, vO + i * DD,
            (i < NL - 1) ? 1 : 0, xout);
    }
    k_poolhead<<<NG, DD, 0, stream>>>(x16b, batch, Wp, bp, (float*)d_out);
}

// Round 6
// 410.242 us; speedup vs baseline: 1.0272x; 1.0272x over previous
//
#include <hip/hip_runtime.h>
#include <hip/hip_bf16.h>

#define NN 40000
#define NE 640000
#define NG 2048
#define DD 128
#define NT 10
#define NL 5
#define NB 80  // dst buckets of 512 nodes

typedef __attribute__((ext_vector_type(8))) short short8;
typedef __attribute__((ext_vector_type(4))) float f32x4;
typedef unsigned short ushort_t;
typedef unsigned char uchar_t;

static __device__ __forceinline__ ushort_t f2b(float f) {
    return __bfloat16_as_ushort(__float2bfloat16(f));
}
static __device__ __forceinline__ float b2f(ushort_t u) {
    return __bfloat162float(__ushort_as_bfloat16(u));
}
static __device__ __forceinline__ uchar_t f2p8(float f) {
    return (uchar_t)(__builtin_amdgcn_cvt_pk_fp8_f32(f, 0.f, 0, false) & 0xFF);
}

// ---------------- fused setup: tables + atom-encode + degree histogram -----
__global__ void __launch_bounds__(256)
k_setup(const float* __restrict__ W1, const float* __restrict__ W2,
        const float* __restrict__ bemb, const int* __restrict__ xa,
        const float* __restrict__ aemb, const int* __restrict__ ei,
        ushort_t* __restrict__ W1P, ushort_t* __restrict__ W2P,
        ushort_t* __restrict__ ebsum16, ushort_t* __restrict__ x16,
        uchar_t* __restrict__ x8, int* __restrict__ deg) {
    int b = blockIdx.x, t = threadIdx.x;
    if (b < 1280) {
        int tid = b * 256 + t;  // < NL*65536
        int layer = tid >> 16;
        int r = tid & 65535;
        int half = r >> 15;
        int q = r & 32767;
        int j = q & 7;
        int lane = (q >> 3) & 63;
        if (half == 0) {
            int kk = (q >> 9) & 3;
            int nt = q >> 11;
            int n = nt * 16 + (lane & 15);
            int k = kk * 32 + (lane >> 4) * 8 + j;
            W1P[layer * 32768 + q] = f2b(W1[(layer * DD + k) * 256 + n]);
        } else {
            int kk = (q >> 9) & 7;
            int nt = q >> 12;
            int n = nt * 16 + (lane & 15);
            int k = kk * 32 + (lane >> 4) * 8 + j;
            W2P[layer * 32768 + q] = f2b(W2[(layer * 256 + k) * DD + n]);
        }
        int d = tid & 127;
        int c = (tid >> 7) & 511;
        const float* bl = bemb + (size_t)layer * 3 * 8 * DD;
        ebsum16[tid] = f2b(bl[(c & 7) * DD + d] + bl[(8 + ((c >> 3) & 7)) * DD + d] +
                           bl[(16 + (c >> 6)) * DD + d]);
    } else if (b < 21280) {
        int half = t >> 7, d = t & 127;
        int n = (b - 1280) * 2 + half;
        __shared__ int idx[2][9];
        if (d < 9) idx[half][d] = xa[n * 9 + d];
        __syncthreads();
        float s = 0.f;
#pragma unroll
        for (int f = 0; f < 9; ++f) s += aemb[(f * 64 + idx[half][f]) * DD + d];
        x16[n * DD + d] = f2b(s);
        x8[n * DD + d] = f2p8(s);
    } else {
        int e = (b - 21280) * 256 + t;
        atomicAdd(&deg[ei[NE + e]], 1);
    }
}

// ---------------- CSR build -----------------------------------------------

__global__ void k_scan1(const int* __restrict__ deg, int* __restrict__ off,
                        int* __restrict__ blksum) {
    int b = blockIdx.x, t = threadIdx.x;
    int i = b * 256 + t;
    __shared__ int s[256];
    int v = (i < NN) ? deg[i] : 0;
    s[t] = v;
    __syncthreads();
    for (int d = 1; d < 256; d <<= 1) {
        int add = (t >= d) ? s[t - d] : 0;
        __syncthreads();
        s[t] += add;
        __syncthreads();
    }
    if (i <= NN) off[i] = s[t] - v;
    if (t == 255) blksum[b] = s[255];
}

__global__ void k_scan2(int* __restrict__ blk) {
    int t = threadIdx.x;
    __shared__ int s[256];
    int v = blk[t];
    s[t] = v;
    __syncthreads();
    for (int d = 1; d < 256; d <<= 1) {
        int add = (t >= d) ? s[t - d] : 0;
        __syncthreads();
        s[t] += add;
        __syncthreads();
    }
    blk[256 + t] = s[t] - v;  // exclusive
}

__global__ void k_scan3(int* __restrict__ off, const int* __restrict__ blk) {
    int b = blockIdx.x, t = threadIdx.x;
    int i = b * 256 + t;
    if (i <= NN) off[i] += blk[256 + b];
}

// Phase A: bin edges by dst bucket into dense runs of ebuf.
__global__ void __launch_bounds__(256)
k_bucket(const int* __restrict__ ei, const int* __restrict__ ea,
         const int* __restrict__ off, int* __restrict__ gbk,
         int2* __restrict__ ebuf) {
    __shared__ int hist[NB];
    __shared__ int sbase[NB];
    int t = threadIdx.x;
    int e0 = blockIdx.x * 1024;
    if (t < NB) hist[t] = 0;
    __syncthreads();
    int rank[4], buck[4], rec[4], dstv[4];
#pragma unroll
    for (int k = 0; k < 4; ++k) {
        int e = e0 + k * 256 + t;
        int src = ei[e];
        int dst = ei[NE + e];
        int a0 = ea[e * 3 + 0], a1 = ea[e * 3 + 1], a2 = ea[e * 3 + 2];
        rec[k] = src | ((a0 | (a1 << 3) | (a2 << 6)) << 16);
        dstv[k] = dst;
        int b = dst >> 9;
        buck[k] = b;
        rank[k] = atomicAdd(&hist[b], 1);
    }
    __syncthreads();
    if (t < NB) sbase[t] = atomicAdd(&gbk[t], hist[t]);
    __syncthreads();
#pragma unroll
    for (int k = 0; k < 4; ++k) {
        int b = buck[k];
        int slot = off[b << 9] + sbase[b] + rank[k];
        ebuf[slot] = make_int2(rec[k], dstv[k]);
    }
}

// Phase B: scatter within L2-resident bucket windows. epack stays PACKED
// (src | code<<16) as a single int.
__global__ void k_scatter2(const int2* __restrict__ ebuf, const int* __restrict__ off,
                           int* __restrict__ cursor, int* __restrict__ epack) {
    int i = blockIdx.x * 256 + threadIdx.x;
    int2 s = ebuf[i];
    int dst = s.y;
    int p = off[dst] + atomicAdd(&cursor[dst], 1);
    epack[p] = s.x;
}

// Gather: wave per node, lane handles 2 dims. 4 nodes/block, 8-deep pipeline
// (round-3 structure). Neighbor rows read from the FP8 mirror (128 B/row,
// half the L2-miss lines/bytes); self term from exact bf16; bond rows L2-hot.
__global__ void __launch_bounds__(256)
k_gather(const ushort_t* __restrict__ xin, const uchar_t* __restrict__ x8in,
         const int* __restrict__ off, const int* __restrict__ epack,
         const ushort_t* __restrict__ ebsum16, const float* __restrict__ eps,
         int layer, ushort_t* __restrict__ h16) {
    int t = threadIdx.x;
    int lane = t & 63;
    int n = blockIdx.x * 4 + (t >> 6);
    const ushort2* x2 = (const ushort2*)xin;
    const ushort_t* x8r = (const ushort_t*)x8in;  // 1 ushort = 2 fp8 dims
    const ushort2* eb2 = (const ushort2*)ebsum16;
    ushort2 xv = x2[n * 64 + lane];
    float es = 1.f + eps[layer];
    float ax = es * b2f(xv.x), ay = es * b2f(xv.y);
    int p = off[n], p1 = off[n + 1];

    int e[8], f[8];
    bool have = (p + 8 <= p1);
    if (have) {
#pragma unroll
        for (int k = 0; k < 8; ++k) e[k] = epack[p + k];
    }
    while (have) {
        int np = p + 8;
        bool nh = (np + 8 <= p1);
        if (nh) {
#pragma unroll
            for (int k = 0; k < 8; ++k) f[k] = epack[np + k];
        }
        ushort2 vv[8];
        ushort_t sp[8];
#pragma unroll
        for (int k = 0; k < 8; ++k) {
            vv[k] = eb2[(e[k] >> 16) * 64 + lane];
            sp[k] = x8r[(e[k] & 0xFFFF) * 64 + lane];
        }
#pragma unroll
        for (int k = 0; k < 8; ++k) {
            float sx = __builtin_amdgcn_cvt_f32_fp8((int)sp[k], 0);
            float sy = __builtin_amdgcn_cvt_f32_fp8((int)sp[k], 1);
            ax += fmaxf(b2f(vv[k].x) + sx, 0.f);
            ay += fmaxf(b2f(vv[k].y) + sy, 0.f);
        }
        p = np;
#pragma unroll
        for (int k = 0; k < 8; ++k) e[k] = f[k];
        have = nh;
    }
    if (p + 4 <= p1) {
        int e4[4];
#pragma unroll
        for (int k = 0; k < 4; ++k) e4[k] = epack[p + k];
        ushort2 vv[4];
        ushort_t sp[4];
#pragma unroll
        for (int k = 0; k < 4; ++k) {
            vv[k] = eb2[(e4[k] >> 16) * 64 + lane];
            sp[k] = x8r[(e4[k] & 0xFFFF) * 64 + lane];
        }
#pragma unroll
        for (int k = 0; k < 4; ++k) {
            float sx = __builtin_amdgcn_cvt_f32_fp8((int)sp[k], 0);
            float sy = __builtin_amdgcn_cvt_f32_fp8((int)sp[k], 1);
            ax += fmaxf(b2f(vv[k].x) + sx, 0.f);
            ay += fmaxf(b2f(vv[k].y) + sy, 0.f);
        }
        p += 4;
    }
    for (; p < p1; ++p) {
        int er = epack[p];
        ushort2 ev = eb2[(er >> 16) * 64 + lane];
        ushort_t sv = x8r[(er & 0xFFFF) * 64 + lane];
        ax += fmaxf(b2f(ev.x) + __builtin_amdgcn_cvt_f32_fp8((int)sv, 0), 0.f);
        ay += fmaxf(b2f(ev.y) + __builtin_amdgcn_cvt_f32_fp8((int)sv, 1), 0.f);
    }
    ushort2 o;
    o.x = f2b(ax);
    o.y = f2b(ay);
    ((ushort2*)h16)[n * 64 + lane] = o;
}

// Fused MLP on MFMA: 32 nodes per block (round-3 config), 256 threads.
// Epilogue additionally emits the FP8 mirror of xout (staged in aS LDS,
// then coalesced int4 stores).
__global__ void __launch_bounds__(256)
k_mlp_mfma(const ushort_t* __restrict__ h16, const ushort_t* __restrict__ W1P,
           const ushort_t* __restrict__ W2P, const float* __restrict__ b1,
           const float* __restrict__ g1, const float* __restrict__ bt1,
           const float* __restrict__ m1, const float* __restrict__ v1,
           const float* __restrict__ b2_, const float* __restrict__ gO,
           const float* __restrict__ btO, const float* __restrict__ mO,
           const float* __restrict__ vO, int relu, ushort_t* __restrict__ xout,
           uchar_t* __restrict__ x8out) {
    __shared__ ushort_t aS[32 * 136];   // 32 rows x 128 (pad +8); reused as fp8 stage
    __shared__ ushort_t mid[32 * 264];  // 32 rows x 256 (pad +8)
    int t = threadIdx.x;
    int wave = t >> 6, lane = t & 63;
    int row0 = blockIdx.x * 32;
    int lrow = lane & 15, quad = lane >> 4;

#pragma unroll
    for (int ps = 0; ps < 2; ++ps) {
        int idx = ps * 256 + t;
        int r = idx >> 4, c = (idx & 15) * 8;
        *(short8*)&aS[r * 136 + c] = *(const short8*)&h16[(row0 + r) * DD + c];
    }
    __syncthreads();

    f32x4 acc1[2][4];
#pragma unroll
    for (int rt = 0; rt < 2; ++rt)
#pragma unroll
        for (int i = 0; i < 4; ++i) acc1[rt][i] = (f32x4){0.f, 0.f, 0.f, 0.f};
#pragma unroll
    for (int kk = 0; kk < 4; ++kk) {
        short8 af0 = *(const short8*)&aS[lrow * 136 + kk * 32 + quad * 8];
        short8 af1 = *(const short8*)&aS[(16 + lrow) * 136 + kk * 32 + quad * 8];
#pragma unroll
        for (int i = 0; i < 4; ++i) {
            int nt = wave * 4 + i;
            short8 bf = *(const short8*)&W1P[((nt * 4 + kk) * 64 + lane) * 8];
            acc1[0][i] = __builtin_amdgcn_mfma_f32_16x16x32_bf16(af0, bf, acc1[0][i], 0, 0, 0);
            acc1[1][i] = __builtin_amdgcn_mfma_f32_16x16x32_bf16(af1, bf, acc1[1][i], 0, 0, 0);
        }
    }
    __syncthreads();  // aS reads done; safe to reuse as fp8 stage
#pragma unroll
    for (int i = 0; i < 4; ++i) {
        int col = (wave * 4 + i) * 16 + lrow;
        float s1 = g1[col] * rsqrtf(v1[col] + 1e-5f);
        float sh = bt1[col] - (m1[col] - b1[col]) * s1;
#pragma unroll
        for (int rt = 0; rt < 2; ++rt)
#pragma unroll
            for (int r = 0; r < 4; ++r) {
                int row = rt * 16 + quad * 4 + r;
                float o = acc1[rt][i][r] * s1 + sh;
                mid[row * 264 + col] = f2b(fmaxf(o, 0.f));
            }
    }
    __syncthreads();

    f32x4 acc2[2][2];
#pragma unroll
    for (int rt = 0; rt < 2; ++rt)
#pragma unroll
        for (int i = 0; i < 2; ++i) acc2[rt][i] = (f32x4){0.f, 0.f, 0.f, 0.f};
#pragma unroll
    for (int kk = 0; kk < 8; ++kk) {
        short8 af0 = *(const short8*)&mid[lrow * 264 + kk * 32 + quad * 8];
        short8 af1 = *(const short8*)&mid[(16 + lrow) * 264 + kk * 32 + quad * 8];
#pragma unroll
        for (int i = 0; i < 2; ++i) {
            int nt = wave * 2 + i;
            short8 bf = *(const short8*)&W2P[((nt * 8 + kk) * 64 + lane) * 8];
            acc2[0][i] = __builtin_amdgcn_mfma_f32_16x16x32_bf16(af0, bf, acc2[0][i], 0, 0, 0);
            acc2[1][i] = __builtin_amdgcn_mfma_f32_16x16x32_bf16(af1, bf, acc2[1][i], 0, 0, 0);
        }
    }
    uchar_t* s8 = (uchar_t*)aS;  // 32*128 = 4096 B stage
#pragma unroll
    for (int i = 0; i < 2; ++i) {
        int col = (wave * 2 + i) * 16 + lrow;
        float s = gO[col] * rsqrtf(vO[col] + 1e-5f);
        float sh = btO[col] - (mO[col] - b2_[col]) * s;
#pragma unroll
        for (int rt = 0; rt < 2; ++rt)
#pragma unroll
            for (int r = 0; r < 4; ++r) {
                int row = rt * 16 + quad * 4 + r;
                float o = acc2[rt][i][r] * s + sh;
                if (relu) o = fmaxf(o, 0.f);
                xout[(row0 + row) * DD + col] = f2b(o);
                s8[row * DD + col] = f2p8(o);
            }
    }
    __syncthreads();
    ((int4*)(x8out + (size_t)row0 * DD))[t] = ((const int4*)s8)[t];
}

// Fused pool+head: block g reduces its node range, then computes out[g].
__global__ void k_poolhead(const ushort_t* __restrict__ x16,
                           const int* __restrict__ batch,
                           const float* __restrict__ Wp, const float* __restrict__ bp,
                           float* __restrict__ out) {
    int g = blockIdx.x, d = threadIdx.x;  // 128 threads
    int lo = 0, hi = NN;
    while (lo < hi) { int m = (lo + hi) >> 1; if (batch[m] < g) lo = m + 1; else hi = m; }
    int start = lo;
    hi = NN;
    while (lo < hi) { int m = (lo + hi) >> 1; if (batch[m] < g + 1) lo = m + 1; else hi = m; }
    int end = lo;
    float s = 0.f;
    for (int n = start; n < end; ++n) s += b2f(x16[n * DD + d]);
    float c = fmaxf((float)(end - start), 1.f);
    __shared__ float p[DD];
    p[d] = s / c;
    __syncthreads();
    if (d < NT) {
        float acc = bp[d];
#pragma unroll 8
        for (int k = 0; k < DD; ++k) acc = fmaf(p[k], Wp[k * NT + d], acc);
        out[g * NT + d] = acc;
    }
}

extern "C" void kernel_launch(void* const* d_in, const int* in_sizes, int n_in,
                              void* d_out, int out_size, void* d_ws, size_t ws_size,
                              hipStream_t stream) {
    const int* x_atom = (const int*)d_in[0];
    const int* edge_index = (const int*)d_in[1];
    const int* edge_attr = (const int*)d_in[2];
    const int* batch = (const int*)d_in[3];
    const float* atom_emb = (const float*)d_in[4];
    const float* bond_emb = (const float*)d_in[5];
    const float* eps = (const float*)d_in[6];
    const float* W1 = (const float*)d_in[7];
    const float* b1 = (const float*)d_in[8];
    const float* g1 = (const float*)d_in[9];
    const float* bt1 = (const float*)d_in[10];
    const float* m1 = (const float*)d_in[11];
    const float* v1 = (const float*)d_in[12];
    const float* W2 = (const float*)d_in[13];
    const float* b2 = (const float*)d_in[14];
    const float* gO = (const float*)d_in[15];
    const float* btO = (const float*)d_in[16];
    const float* mO = (const float*)d_in[17];
    const float* vO = (const float*)d_in[18];
    const float* Wp = (const float*)d_in[19];
    const float* bp = (const float*)d_in[20];

    ushort_t* x16a = (ushort_t*)d_ws;        // N*D bf16
    ushort_t* x16b = x16a + NN * DD;         // N*D bf16
    ushort_t* h16 = x16b + NN * DD;          // N*D bf16
    ushort_t* W1P = h16 + NN * DD;           // NL*32768 bf16
    ushort_t* W2P = W1P + NL * 32768;        // NL*32768 bf16
    ushort_t* ebsum16 = W2P + NL * 32768;    // NL*512*128 bf16
    uchar_t* x8a = (uchar_t*)(ebsum16 + NL * 65536);  // N*D fp8
    uchar_t* x8b = x8a + NN * DD;            // N*D fp8
    int* deg = (int*)(x8b + NN * DD);        // 40000
    int* off = deg + NN;                     // 40064
    int* blk = off + 40064;                  // 512
    int* cursor = blk + 512;                 // 40000
    int* gbk = cursor + NN;                  // 128
    int* epack = gbk + 128;                  // NE int (packed src|code<<16)
    int2* ebuf = (int2*)(epack + NE);        // NE int2

    hipMemsetAsync(deg, 0, (NN + 40064 + 512 + NN + 128) * sizeof(int), stream);

    k_setup<<<23780, 256, 0, stream>>>(W1, W2, bond_emb, x_atom, atom_emb,
                                       edge_index, W1P, W2P, ebsum16, x16a, x8a, deg);
    k_scan1<<<157, 256, 0, stream>>>(deg, off, blk);
    k_scan2<<<1, 256, 0, stream>>>(blk);
    k_scan3<<<157, 256, 0, stream>>>(off, blk);
    k_bucket<<<NE / 1024, 256, 0, stream>>>(edge_index, edge_attr, off, gbk, ebuf);
    k_scatter2<<<NE / 256, 256, 0, stream>>>(ebuf, off, cursor, epack);

    for (int i = 0; i < NL; ++i) {
        ushort_t* xin = (i & 1) ? x16b : x16a;
        ushort_t* xout = (i & 1) ? x16a : x16b;
        uchar_t* x8in = (i & 1) ? x8b : x8a;
        uchar_t* x8out = (i & 1) ? x8a : x8b;
        k_gather<<<NN / 4, 256, 0, stream>>>(xin, x8in, off, epack,
                                             ebsum16 + i * 65536, eps, i, h16);
        k_mlp_mfma<<<NN / 32, 256, 0, stream>>>(
            h16, W1P + (size_t)i * 32768, W2P + (size_t)i * 32768, b1 + i * 256,
            g1 + i * 256, bt1 + i * 256, m1 + i * 256, v1 + i * 256, b2 + i * DD,
            gO + i * DD, btO + i * DD, mO + i * DD, vO + i * DD,
            (i < NL - 1) ? 1 : 0, xout, x8out);
    }
    k_poolhead<<<NG, DD, 0, stream>>>(x16b, batch, Wp, bp, (float*)d_out);
}

// Round 8
// 405.973 us; speedup vs baseline: 1.0380x; 1.0105x over previous
//
#include <hip/hip_runtime.h>
#include <hip/hip_bf16.h>

#define NN 40000
#define NE 640000
#define NG 2048
#define DD 128
#define NT 10
#define NL 5
#define NB 80  // dst buckets of 512 nodes

typedef __attribute__((ext_vector_type(8))) short short8;
typedef __attribute__((ext_vector_type(8))) float f32x8;
typedef __attribute__((ext_vector_type(4))) float f32x4;
typedef unsigned short ushort_t;
typedef unsigned char uchar_t;

static __device__ __forceinline__ ushort_t f2b(float f) {
    return __bfloat16_as_ushort(__float2bfloat16(f));
}
static __device__ __forceinline__ float b2f(ushort_t u) {
    return __bfloat162float(__ushort_as_bfloat16(u));
}
static __device__ __forceinline__ uchar_t f2p8(float f) {
    return (uchar_t)(__builtin_amdgcn_cvt_pk_fp8_f32(f, 0.f, 0, false) & 0xFF);
}

// ---------------- fused setup: tables + atom-encode + degree histogram -----
// Atom-encode restructured: thread owns 8 dims (f32x8 loads), 16 nodes/block.
__global__ void __launch_bounds__(256)
k_setup(const float* __restrict__ W1, const float* __restrict__ W2,
        const float* __restrict__ bemb, const int* __restrict__ xa,
        const float* __restrict__ aemb, const int* __restrict__ ei,
        ushort_t* __restrict__ W1P, ushort_t* __restrict__ W2P,
        ushort_t* __restrict__ ebsum16, ushort_t* __restrict__ x16,
        uchar_t* __restrict__ x8, int* __restrict__ deg) {
    int b = blockIdx.x, t = threadIdx.x;
    if (b < 1280) {
        int tid = b * 256 + t;  // < NL*65536
        int layer = tid >> 16;
        int r = tid & 65535;
        int half = r >> 15;
        int q = r & 32767;
        int j = q & 7;
        int lane = (q >> 3) & 63;
        if (half == 0) {
            int kk = (q >> 9) & 3;
            int nt = q >> 11;
            int n = nt * 16 + (lane & 15);
            int k = kk * 32 + (lane >> 4) * 8 + j;
            W1P[layer * 32768 + q] = f2b(W1[(layer * DD + k) * 256 + n]);
        } else {
            int kk = (q >> 9) & 7;
            int nt = q >> 12;
            int n = nt * 16 + (lane & 15);
            int k = kk * 32 + (lane >> 4) * 8 + j;
            W2P[layer * 32768 + q] = f2b(W2[(layer * 256 + k) * DD + n]);
        }
        int d = tid & 127;
        int c = (tid >> 7) & 511;
        const float* bl = bemb + (size_t)layer * 3 * 8 * DD;
        ebsum16[tid] = f2b(bl[(c & 7) * DD + d] + bl[(8 + ((c >> 3) & 7)) * DD + d] +
                           bl[(16 + (c >> 6)) * DD + d]);
    } else if (b < 3780) {
        // atom-encode: 16 nodes/block, thread = (node_local = t>>4, dcol = t&15)
        int bb = b - 1280;
        __shared__ int idxS[144];
        if (t < 144) idxS[t] = xa[bb * 144 + t];
        __syncthreads();
        int nl = t >> 4, dcol = t & 15;
        int n = bb * 16 + nl;
        float acc[8];
#pragma unroll
        for (int k = 0; k < 8; ++k) acc[k] = 0.f;
#pragma unroll
        for (int f = 0; f < 9; ++f) {
            const f32x8 v = *(const f32x8*)&aemb[(f * 64 + idxS[nl * 9 + f]) * DD + dcol * 8];
#pragma unroll
            for (int k = 0; k < 8; ++k) acc[k] += v[k];
        }
        short8 o16;
#pragma unroll
        for (int k = 0; k < 8; ++k) o16[k] = (short)f2b(acc[k]);
        *(short8*)&x16[(size_t)n * DD + dcol * 8] = o16;
        unsigned int lo = 0, hi = 0;
        lo = __builtin_amdgcn_cvt_pk_fp8_f32(acc[0], acc[1], lo, false);
        lo = __builtin_amdgcn_cvt_pk_fp8_f32(acc[2], acc[3], lo, true);
        hi = __builtin_amdgcn_cvt_pk_fp8_f32(acc[4], acc[5], hi, false);
        hi = __builtin_amdgcn_cvt_pk_fp8_f32(acc[6], acc[7], hi, true);
        *(uint2*)&x8[(size_t)n * DD + dcol * 8] = make_uint2(lo, hi);
    } else {
        int e = (b - 3780) * 256 + t;
        atomicAdd(&deg[ei[NE + e]], 1);
    }
}

// ---------------- CSR build -----------------------------------------------

__global__ void k_scan1(const int* __restrict__ deg, int* __restrict__ off,
                        int* __restrict__ blksum) {
    int b = blockIdx.x, t = threadIdx.x;
    int i = b * 256 + t;
    __shared__ int s[256];
    int v = (i < NN) ? deg[i] : 0;
    s[t] = v;
    __syncthreads();
    for (int d = 1; d < 256; d <<= 1) {
        int add = (t >= d) ? s[t - d] : 0;
        __syncthreads();
        s[t] += add;
        __syncthreads();
    }
    if (i <= NN) off[i] = s[t] - v;
    if (t == 255) blksum[b] = s[255];
}

__global__ void k_scan2(int* __restrict__ blk) {
    int t = threadIdx.x;
    __shared__ int s[256];
    int v = blk[t];
    s[t] = v;
    __syncthreads();
    for (int d = 1; d < 256; d <<= 1) {
        int add = (t >= d) ? s[t - d] : 0;
        __syncthreads();
        s[t] += add;
        __syncthreads();
    }
    blk[256 + t] = s[t] - v;  // exclusive
}

__global__ void k_scan3(int* __restrict__ off, const int* __restrict__ blk) {
    int b = blockIdx.x, t = threadIdx.x;
    int i = b * 256 + t;
    if (i <= NN) off[i] += blk[256 + b];
}

// Phase A: bin edges by dst bucket into dense runs of ebuf.
__global__ void __launch_bounds__(256)
k_bucket(const int* __restrict__ ei, const int* __restrict__ ea,
         const int* __restrict__ off, int* __restrict__ gbk,
         int2* __restrict__ ebuf) {
    __shared__ int hist[NB];
    __shared__ int sbase[NB];
    int t = threadIdx.x;
    int e0 = blockIdx.x * 1024;
    if (t < NB) hist[t] = 0;
    __syncthreads();
    int rank[4], buck[4], rec[4], dstv[4];
#pragma unroll
    for (int k = 0; k < 4; ++k) {
        int e = e0 + k * 256 + t;
        int src = ei[e];
        int dst = ei[NE + e];
        int a0 = ea[e * 3 + 0], a1 = ea[e * 3 + 1], a2 = ea[e * 3 + 2];
        rec[k] = src | ((a0 | (a1 << 3) | (a2 << 6)) << 16);
        dstv[k] = dst;
        int b = dst >> 9;
        buck[k] = b;
        rank[k] = atomicAdd(&hist[b], 1);
    }
    __syncthreads();
    if (t < NB) sbase[t] = atomicAdd(&gbk[t], hist[t]);
    __syncthreads();
#pragma unroll
    for (int k = 0; k < 4; ++k) {
        int b = buck[k];
        int slot = off[b << 9] + sbase[b] + rank[k];
        ebuf[slot] = make_int2(rec[k], dstv[k]);
    }
}

// Phase B: scatter within L2-resident bucket windows. epack stays PACKED
// (src | code<<16) as a single int.
__global__ void k_scatter2(const int2* __restrict__ ebuf, const int* __restrict__ off,
                           int* __restrict__ cursor, int* __restrict__ epack) {
    int i = blockIdx.x * 256 + threadIdx.x;
    int2 s = ebuf[i];
    int dst = s.y;
    int p = off[dst] + atomicAdd(&cursor[dst], 1);
    epack[p] = s.x;
}

// Gather: wave per node, lane handles 2 dims. 4 nodes/block, 8-deep pipeline
// (round-3 structure). Neighbor rows read from the FP8 mirror (128 B/row);
// self term from exact bf16; bond rows L2-hot.
__global__ void __launch_bounds__(256)
k_gather(const ushort_t* __restrict__ xin, const uchar_t* __restrict__ x8in,
         const int* __restrict__ off, const int* __restrict__ epack,
         const ushort_t* __restrict__ ebsum16, const float* __restrict__ eps,
         int layer, ushort_t* __restrict__ h16) {
    int t = threadIdx.x;
    int lane = t & 63;
    int n = blockIdx.x * 4 + (t >> 6);
    const ushort2* x2 = (const ushort2*)xin;
    const ushort_t* x8r = (const ushort_t*)x8in;  // 1 ushort = 2 fp8 dims
    const ushort2* eb2 = (const ushort2*)ebsum16;
    ushort2 xv = x2[n * 64 + lane];
    float es = 1.f + eps[layer];
    float ax = es * b2f(xv.x), ay = es * b2f(xv.y);
    int p = off[n], p1 = off[n + 1];

    int e[8], f[8];
    bool have = (p + 8 <= p1);
    if (have) {
#pragma unroll
        for (int k = 0; k < 8; ++k) e[k] = epack[p + k];
    }
    while (have) {
        int np = p + 8;
        bool nh = (np + 8 <= p1);
        if (nh) {
#pragma unroll
            for (int k = 0; k < 8; ++k) f[k] = epack[np + k];
        }
        ushort2 vv[8];
        ushort_t sp[8];
#pragma unroll
        for (int k = 0; k < 8; ++k) {
            vv[k] = eb2[(e[k] >> 16) * 64 + lane];
            sp[k] = x8r[(e[k] & 0xFFFF) * 64 + lane];
        }
#pragma unroll
        for (int k = 0; k < 8; ++k) {
            float sx = __builtin_amdgcn_cvt_f32_fp8((int)sp[k], 0);
            float sy = __builtin_amdgcn_cvt_f32_fp8((int)sp[k], 1);
            ax += fmaxf(b2f(vv[k].x) + sx, 0.f);
            ay += fmaxf(b2f(vv[k].y) + sy, 0.f);
        }
        p = np;
#pragma unroll
        for (int k = 0; k < 8; ++k) e[k] = f[k];
        have = nh;
    }
    if (p + 4 <= p1) {
        int e4[4];
#pragma unroll
        for (int k = 0; k < 4; ++k) e4[k] = epack[p + k];
        ushort2 vv[4];
        ushort_t sp[4];
#pragma unroll
        for (int k = 0; k < 4; ++k) {
            vv[k] = eb2[(e4[k] >> 16) * 64 + lane];
            sp[k] = x8r[(e4[k] & 0xFFFF) * 64 + lane];
        }
#pragma unroll
        for (int k = 0; k < 4; ++k) {
            float sx = __builtin_amdgcn_cvt_f32_fp8((int)sp[k], 0);
            float sy = __builtin_amdgcn_cvt_f32_fp8((int)sp[k], 1);
            ax += fmaxf(b2f(vv[k].x) + sx, 0.f);
            ay += fmaxf(b2f(vv[k].y) + sy, 0.f);
        }
        p += 4;
    }
    for (; p < p1; ++p) {
        int er = epack[p];
        ushort2 ev = eb2[(er >> 16) * 64 + lane];
        ushort_t sv = x8r[(er & 0xFFFF) * 64 + lane];
        ax += fmaxf(b2f(ev.x) + __builtin_amdgcn_cvt_f32_fp8((int)sv, 0), 0.f);
        ay += fmaxf(b2f(ev.y) + __builtin_amdgcn_cvt_f32_fp8((int)sv, 1), 0.f);
    }
    ushort2 o;
    o.x = f2b(ax);
    o.y = f2b(ay);
    ((ushort2*)h16)[n * 64 + lane] = o;
}

// Fused MLP on MFMA: 32 nodes per block, 256 threads. Epilogue additionally
// emits the FP8 mirror of xout (staged in aS LDS, then coalesced int4 stores).
__global__ void __launch_bounds__(256)
k_mlp_mfma(const ushort_t* __restrict__ h16, const ushort_t* __restrict__ W1P,
           const ushort_t* __restrict__ W2P, const float* __restrict__ b1,
           const float* __restrict__ g1, const float* __restrict__ bt1,
           const float* __restrict__ m1, const float* __restrict__ v1,
           const float* __restrict__ b2_, const float* __restrict__ gO,
           const float* __restrict__ btO, const float* __restrict__ mO,
           const float* __restrict__ vO, int relu, ushort_t* __restrict__ xout,
           uchar_t* __restrict__ x8out) {
    __shared__ ushort_t aS[32 * 136];   // 32 rows x 128 (pad +8); reused as fp8 stage
    __shared__ ushort_t mid[32 * 264];  // 32 rows x 256 (pad +8)
    int t = threadIdx.x;
    int wave = t >> 6, lane = t & 63;
    int row0 = blockIdx.x * 32;
    int lrow = lane & 15, quad = lane >> 4;

#pragma unroll
    for (int ps = 0; ps < 2; ++ps) {
        int idx = ps * 256 + t;
        int r = idx >> 4, c = (idx & 15) * 8;
        *(short8*)&aS[r * 136 + c] = *(const short8*)&h16[(row0 + r) * DD + c];
    }
    __syncthreads();

    f32x4 acc1[2][4];
#pragma unroll
    for (int rt = 0; rt < 2; ++rt)
#pragma unroll
        for (int i = 0; i < 4; ++i) acc1[rt][i] = (f32x4){0.f, 0.f, 0.f, 0.f};
#pragma unroll
    for (int kk = 0; kk < 4; ++kk) {
        short8 af0 = *(const short8*)&aS[lrow * 136 + kk * 32 + quad * 8];
        short8 af1 = *(const short8*)&aS[(16 + lrow) * 136 + kk * 32 + quad * 8];
#pragma unroll
        for (int i = 0; i < 4; ++i) {
            int nt = wave * 4 + i;
            short8 bf = *(const short8*)&W1P[((nt * 4 + kk) * 64 + lane) * 8];
            acc1[0][i] = __builtin_amdgcn_mfma_f32_16x16x32_bf16(af0, bf, acc1[0][i], 0, 0, 0);
            acc1[1][i] = __builtin_amdgcn_mfma_f32_16x16x32_bf16(af1, bf, acc1[1][i], 0, 0, 0);
        }
    }
    __syncthreads();  // aS reads done; safe to reuse as fp8 stage
#pragma unroll
    for (int i = 0; i < 4; ++i) {
        int col = (wave * 4 + i) * 16 + lrow;
        float s1 = g1[col] * rsqrtf(v1[col] + 1e-5f);
        float sh = bt1[col] - (m1[col] - b1[col]) * s1;
#pragma unroll
        for (int rt = 0; rt < 2; ++rt)
#pragma unroll
            for (int r = 0; r < 4; ++r) {
                int row = rt * 16 + quad * 4 + r;
                float o = acc1[rt][i][r] * s1 + sh;
                mid[row * 264 + col] = f2b(fmaxf(o, 0.f));
            }
    }
    __syncthreads();

    f32x4 acc2[2][2];
#pragma unroll
    for (int rt = 0; rt < 2; ++rt)
#pragma unroll
        for (int i = 0; i < 2; ++i) acc2[rt][i] = (f32x4){0.f, 0.f, 0.f, 0.f};
#pragma unroll
    for (int kk = 0; kk < 8; ++kk) {
        short8 af0 = *(const short8*)&mid[lrow * 264 + kk * 32 + quad * 8];
        short8 af1 = *(const short8*)&mid[(16 + lrow) * 264 + kk * 32 + quad * 8];
#pragma unroll
        for (int i = 0; i < 2; ++i) {
            int nt = wave * 2 + i;
            short8 bf = *(const short8*)&W2P[((nt * 8 + kk) * 64 + lane) * 8];
            acc2[0][i] = __builtin_amdgcn_mfma_f32_16x16x32_bf16(af0, bf, acc2[0][i], 0, 0, 0);
            acc2[1][i] = __builtin_amdgcn_mfma_f32_16x16x32_bf16(af1, bf, acc2[1][i], 0, 0, 0);
        }
    }
    uchar_t* s8 = (uchar_t*)aS;  // 32*128 = 4096 B stage
#pragma unroll
    for (int i = 0; i < 2; ++i) {
        int col = (wave * 2 + i) * 16 + lrow;
        float s = gO[col] * rsqrtf(vO[col] + 1e-5f);
        float sh = btO[col] - (mO[col] - b2_[col]) * s;
#pragma unroll
        for (int rt = 0; rt < 2; ++rt)
#pragma unroll
            for (int r = 0; r < 4; ++r) {
                int row = rt * 16 + quad * 4 + r;
                float o = acc2[rt][i][r] * s + sh;
                if (relu) o = fmaxf(o, 0.f);
                xout[(row0 + row) * DD + col] = f2b(o);
                s8[row * DD + col] = f2p8(o);
            }
    }
    __syncthreads();
    ((int4*)(x8out + (size_t)row0 * DD))[t] = ((const int4*)s8)[t];
}

// Fused pool+head: block g reduces its node range, then computes out[g].
__global__ void k_poolhead(const ushort_t* __restrict__ x16,
                           const int* __restrict__ batch,
                           const float* __restrict__ Wp, const float* __restrict__ bp,
                           float* __restrict__ out) {
    int g = blockIdx.x, d = threadIdx.x;  // 128 threads
    int lo = 0, hi = NN;
    while (lo < hi) { int m = (lo + hi) >> 1; if (batch[m] < g) lo = m + 1; else hi = m; }
    int start = lo;
    hi = NN;
    while (lo < hi) { int m = (lo + hi) >> 1; if (batch[m] < g + 1) lo = m + 1; else hi = m; }
    int end = lo;
    float s = 0.f;
    for (int n = start; n < end; ++n) s += b2f(x16[n * DD + d]);
    float c = fmaxf((float)(end - start), 1.f);
    __shared__ float p[DD];
    p[d] = s / c;
    __syncthreads();
    if (d < NT) {
        float acc = bp[d];
#pragma unroll 8
        for (int k = 0; k < DD; ++k) acc = fmaf(p[k], Wp[k * NT + d], acc);
        out[g * NT + d] = acc;
    }
}

extern "C" void kernel_launch(void* const* d_in, const int* in_sizes, int n_in,
                              void* d_out, int out_size, void* d_ws, size_t ws_size,
                              hipStream_t stream) {
    const int* x_atom = (const int*)d_in[0];
    const int* edge_index = (const int*)d_in[1];
    const int* edge_attr = (const int*)d_in[2];
    const int* batch = (const int*)d_in[3];
    const float* atom_emb = (const float*)d_in[4];
    const float* bond_emb = (const float*)d_in[5];
    const float* eps = (const float*)d_in[6];
    const float* W1 = (const float*)d_in[7];
    const float* b1 = (const float*)d_in[8];
    const float* g1 = (const float*)d_in[9];
    const float* bt1 = (const float*)d_in[10];
    const float* m1 = (const float*)d_in[11];
    const float* v1 = (const float*)d_in[12];
    const float* W2 = (const float*)d_in[13];
    const float* b2 = (const float*)d_in[14];
    const float* gO = (const float*)d_in[15];
    const float* btO = (const float*)d_in[16];
    const float* mO = (const float*)d_in[17];
    const float* vO = (const float*)d_in[18];
    const float* Wp = (const float*)d_in[19];
    const float* bp = (const float*)d_in[20];

    ushort_t* x16a = (ushort_t*)d_ws;        // N*D bf16
    ushort_t* x16b = x16a + NN * DD;         // N*D bf16
    ushort_t* h16 = x16b + NN * DD;          // N*D bf16
    ushort_t* W1P = h16 + NN * DD;           // NL*32768 bf16
    ushort_t* W2P = W1P + NL * 32768;        // NL*32768 bf16
    ushort_t* ebsum16 = W2P + NL * 32768;    // NL*512*128 bf16
    uchar_t* x8a = (uchar_t*)(ebsum16 + NL * 65536);  // N*D fp8
    uchar_t* x8b = x8a + NN * DD;            // N*D fp8
    int* deg = (int*)(x8b + NN * DD);        // 40000
    int* off = deg + NN;                     // 40064
    int* blk = off + 40064;                  // 512
    int* cursor = blk + 512;                 // 40000
    int* gbk = cursor + NN;                  // 128
    int* epack = gbk + 128;                  // NE int (packed src|code<<16)
    int2* ebuf = (int2*)(epack + NE);        // NE int2

    hipMemsetAsync(deg, 0, (NN + 40064 + 512 + NN + 128) * sizeof(int), stream);

    k_setup<<<6280, 256, 0, stream>>>(W1, W2, bond_emb, x_atom, atom_emb,
                                      edge_index, W1P, W2P, ebsum16, x16a, x8a, deg);
    k_scan1<<<157, 256, 0, stream>>>(deg, off, blk);
    k_scan2<<<1, 256, 0, stream>>>(blk);
    k_scan3<<<157, 256, 0, stream>>>(off, blk);
    k_bucket<<<NE / 1024, 256, 0, stream>>>(edge_index, edge_attr, off, gbk, ebuf);
    k_scatter2<<<NE / 256, 256, 0, stream>>>(ebuf, off, cursor, epack);

    for (int i = 0; i < NL; ++i) {
        ushort_t* xin = (i & 1) ? x16b : x16a;
        ushort_t* xout = (i & 1) ? x16a : x16b;
        uchar_t* x8in = (i & 1) ? x8b : x8a;
        uchar_t* x8out = (i & 1) ? x8a : x8b;
        k_gather<<<NN / 4, 256, 0, stream>>>(xin, x8in, off, epack,
                                             ebsum16 + i * 65536, eps, i, h16);
        k_mlp_mfma<<<NN / 32, 256, 0, stream>>>(
            h16, W1P + (size_t)i * 32768, W2P + (size_t)i * 32768, b1 + i * 256,
            g1 + i * 256, bt1 + i * 256, m1 + i * 256, v1 + i * 256, b2 + i * DD,
            gO + i * DD, btO + i * DD, mO + i * DD, vO + i * DD,
            (i < NL - 1) ? 1 : 0, xout, x8out);
    }
    k_poolhead<<<NG, DD, 0, stream>>>(x16b, batch, Wp, bp, (float*)d_out);
}

// Round 9
// 383.190 us; speedup vs baseline: 1.0997x; 1.0595x over previous
//
#include <hip/hip_runtime.h>
#include <hip/hip_bf16.h>

#define NN 40000
#define NE 640000
#define NG 2048
#define DD 128
#define NT 10
#define NL 5
#define NB 80  // dst buckets of 512 nodes

typedef __attribute__((ext_vector_type(8))) short short8;
typedef __attribute__((ext_vector_type(8))) float f32x8;
typedef __attribute__((ext_vector_type(4))) float f32x4;
typedef unsigned short ushort_t;
typedef unsigned char uchar_t;

static __device__ __forceinline__ ushort_t f2b(float f) {
    return __bfloat16_as_ushort(__float2bfloat16(f));
}
static __device__ __forceinline__ float b2f(ushort_t u) {
    return __bfloat162float(__ushort_as_bfloat16(u));
}
static __device__ __forceinline__ uchar_t f2p8(float f) {
    return (uchar_t)(__builtin_amdgcn_cvt_pk_fp8_f32(f, 0.f, 0, false) & 0xFF);
}

// ------- fused setup: tables + atom-encode + BUCKET count (80 bins) --------
// No node-granular global atomics: bucket counts via LDS hist + 80 adds/blk.
__global__ void __launch_bounds__(256)
k_setup(const float* __restrict__ W1, const float* __restrict__ W2,
        const float* __restrict__ bemb, const int* __restrict__ xa,
        const float* __restrict__ aemb, const int* __restrict__ ei,
        ushort_t* __restrict__ W1P, ushort_t* __restrict__ W2P,
        ushort_t* __restrict__ ebsum16, ushort_t* __restrict__ x16,
        uchar_t* __restrict__ x8, int* __restrict__ gcnt) {
    int b = blockIdx.x, t = threadIdx.x;
    if (b < 1280) {
        int tid = b * 256 + t;  // < NL*65536
        int layer = tid >> 16;
        int r = tid & 65535;
        int half = r >> 15;
        int q = r & 32767;
        int j = q & 7;
        int lane = (q >> 3) & 63;
        if (half == 0) {
            int kk = (q >> 9) & 3;
            int nt = q >> 11;
            int n = nt * 16 + (lane & 15);
            int k = kk * 32 + (lane >> 4) * 8 + j;
            W1P[layer * 32768 + q] = f2b(W1[(layer * DD + k) * 256 + n]);
        } else {
            int kk = (q >> 9) & 7;
            int nt = q >> 12;
            int n = nt * 16 + (lane & 15);
            int k = kk * 32 + (lane >> 4) * 8 + j;
            W2P[layer * 32768 + q] = f2b(W2[(layer * 256 + k) * DD + n]);
        }
        int d = tid & 127;
        int c = (tid >> 7) & 511;
        const float* bl = bemb + (size_t)layer * 3 * 8 * DD;
        ebsum16[tid] = f2b(bl[(c & 7) * DD + d] + bl[(8 + ((c >> 3) & 7)) * DD + d] +
                           bl[(16 + (c >> 6)) * DD + d]);
    } else if (b < 3780) {
        // atom-encode: 16 nodes/block, thread = (node_local = t>>4, dcol = t&15)
        int bb = b - 1280;
        __shared__ int idxS[144];
        if (t < 144) idxS[t] = xa[bb * 144 + t];
        __syncthreads();
        int nl = t >> 4, dcol = t & 15;
        int n = bb * 16 + nl;
        float acc[8];
#pragma unroll
        for (int k = 0; k < 8; ++k) acc[k] = 0.f;
#pragma unroll
        for (int f = 0; f < 9; ++f) {
            const f32x8 v = *(const f32x8*)&aemb[(f * 64 + idxS[nl * 9 + f]) * DD + dcol * 8];
#pragma unroll
            for (int k = 0; k < 8; ++k) acc[k] += v[k];
        }
        short8 o16;
#pragma unroll
        for (int k = 0; k < 8; ++k) o16[k] = (short)f2b(acc[k]);
        *(short8*)&x16[(size_t)n * DD + dcol * 8] = o16;
        unsigned int lo = 0, hi = 0;
        lo = __builtin_amdgcn_cvt_pk_fp8_f32(acc[0], acc[1], lo, false);
        lo = __builtin_amdgcn_cvt_pk_fp8_f32(acc[2], acc[3], lo, true);
        hi = __builtin_amdgcn_cvt_pk_fp8_f32(acc[4], acc[5], hi, false);
        hi = __builtin_amdgcn_cvt_pk_fp8_f32(acc[6], acc[7], hi, true);
        *(uint2*)&x8[(size_t)n * DD + dcol * 8] = make_uint2(lo, hi);
    } else {
        // bucket count: 1024 edges/block, LDS hist of 80 bins
        __shared__ int hist[NB];
        int e0 = (b - 3780) * 1024;
        if (t < NB) hist[t] = 0;
        __syncthreads();
#pragma unroll
        for (int k = 0; k < 4; ++k) {
            int e = e0 + k * 256 + t;
            atomicAdd(&hist[ei[NE + e] >> 9], 1);
        }
        __syncthreads();
        if (t < NB) atomicAdd(&gcnt[t], hist[t]);
    }
}

// Exclusive scan of the 80 bucket counts -> bbase[0..80].
__global__ void k_bscan(const int* __restrict__ gcnt, int* __restrict__ bbase) {
    int t = threadIdx.x;  // 128
    __shared__ int s[128];
    int v = (t < NB) ? gcnt[t] : 0;
    s[t] = v;
    __syncthreads();
    for (int d = 1; d < 128; d <<= 1) {
        int add = (t >= d) ? s[t - d] : 0;
        __syncthreads();
        s[t] += add;
        __syncthreads();
    }
    if (t <= NB) bbase[t] = s[t] - v;
}

// Phase A: bin edges by dst bucket into dense runs of ebuf (bases = bbase).
__global__ void __launch_bounds__(256)
k_bucket(const int* __restrict__ ei, const int* __restrict__ ea,
         const int* __restrict__ bbase, int* __restrict__ gbk,
         int2* __restrict__ ebuf) {
    __shared__ int hist[NB];
    __shared__ int sbase[NB];
    int t = threadIdx.x;
    int e0 = blockIdx.x * 1024;
    if (t < NB) hist[t] = 0;
    __syncthreads();
    int rank[4], buck[4], rec[4], dstv[4];
#pragma unroll
    for (int k = 0; k < 4; ++k) {
        int e = e0 + k * 256 + t;
        int src = ei[e];
        int dst = ei[NE + e];
        int a0 = ea[e * 3 + 0], a1 = ea[e * 3 + 1], a2 = ea[e * 3 + 2];
        rec[k] = src | ((a0 | (a1 << 3) | (a2 << 6)) << 16);
        dstv[k] = dst;
        int b = dst >> 9;
        buck[k] = b;
        rank[k] = atomicAdd(&hist[b], 1);
    }
    __syncthreads();
    if (t < NB) sbase[t] = atomicAdd(&gbk[t], hist[t]);
    __syncthreads();
#pragma unroll
    for (int k = 0; k < 4; ++k) {
        int b = buck[k];
        int slot = bbase[b] + sbase[b] + rank[k];
        ebuf[slot] = make_int2(rec[k], dstv[k]);
    }
}

// Per-bucket CSR + scatter: one block per bucket (512 nodes, ~8000 edges).
// LDS 512-bin histogram -> block scan -> off[]; LDS-cursor scatter -> epack.
// All heavy atomics are LDS-scope.
__global__ void __launch_bounds__(256)
k_csr(const int2* __restrict__ ebuf, const int* __restrict__ bbase,
      int* __restrict__ off, int* __restrict__ epack) {
    __shared__ int cnt[512];
    __shared__ int cur[512];
    __shared__ int sc[256];
    int b = blockIdx.x, t = threadIdx.x;
    int base = bbase[b], end = bbase[b + 1];
    cnt[t] = 0; cnt[t + 256] = 0;
    cur[t] = 0; cur[t + 256] = 0;
    __syncthreads();
    for (int i = base + t; i < end; i += 256)
        atomicAdd(&cnt[ebuf[i].y & 511], 1);
    __syncthreads();
    int a = cnt[2 * t], c2 = cnt[2 * t + 1];
    sc[t] = a + c2;
    __syncthreads();
    for (int d = 1; d < 256; d <<= 1) {
        int add = (t >= d) ? sc[t - d] : 0;
        __syncthreads();
        sc[t] += add;
        __syncthreads();
    }
    int ex = sc[t] - (a + c2);  // exclusive sum of pairs before this pair
    cnt[2 * t] = ex;
    cnt[2 * t + 1] = ex + a;
    int n0 = (b << 9) + 2 * t;
    if (n0 <= NN) off[n0] = base + ex;
    if (n0 + 1 <= NN) off[n0 + 1] = base + ex + a;
    __syncthreads();
    for (int i = base + t; i < end; i += 256) {
        int2 s = ebuf[i];
        int l = s.y & 511;
        int r = atomicAdd(&cur[l], 1);
        epack[base + cnt[l] + r] = s.x;
    }
}

// Gather: wave per node, lane handles 2 dims. 4 nodes/block, 8-deep pipeline
// (round-3 structure). Neighbor rows read from the FP8 mirror (128 B/row);
// self term from exact bf16; bond rows L2-hot.
__global__ void __launch_bounds__(256)
k_gather(const ushort_t* __restrict__ xin, const uchar_t* __restrict__ x8in,
         const int* __restrict__ off, const int* __restrict__ epack,
         const ushort_t* __restrict__ ebsum16, const float* __restrict__ eps,
         int layer, ushort_t* __restrict__ h16) {
    int t = threadIdx.x;
    int lane = t & 63;
    int n = blockIdx.x * 4 + (t >> 6);
    const ushort2* x2 = (const ushort2*)xin;
    const ushort_t* x8r = (const ushort_t*)x8in;  // 1 ushort = 2 fp8 dims
    const ushort2* eb2 = (const ushort2*)ebsum16;
    ushort2 xv = x2[n * 64 + lane];
    float es = 1.f + eps[layer];
    float ax = es * b2f(xv.x), ay = es * b2f(xv.y);
    int p = off[n], p1 = off[n + 1];

    int e[8], f[8];
    bool have = (p + 8 <= p1);
    if (have) {
#pragma unroll
        for (int k = 0; k < 8; ++k) e[k] = epack[p + k];
    }
    while (have) {
        int np = p + 8;
        bool nh = (np + 8 <= p1);
        if (nh) {
#pragma unroll
            for (int k = 0; k < 8; ++k) f[k] = epack[np + k];
        }
        ushort2 vv[8];
        ushort_t sp[8];
#pragma unroll
        for (int k = 0; k < 8; ++k) {
            vv[k] = eb2[(e[k] >> 16) * 64 + lane];
            sp[k] = x8r[(e[k] & 0xFFFF) * 64 + lane];
        }
#pragma unroll
        for (int k = 0; k < 8; ++k) {
            float sx = __builtin_amdgcn_cvt_f32_fp8((int)sp[k], 0);
            float sy = __builtin_amdgcn_cvt_f32_fp8((int)sp[k], 1);
            ax += fmaxf(b2f(vv[k].x) + sx, 0.f);
            ay += fmaxf(b2f(vv[k].y) + sy, 0.f);
        }
        p = np;
#pragma unroll
        for (int k = 0; k < 8; ++k) e[k] = f[k];
        have = nh;
    }
    if (p + 4 <= p1) {
        int e4[4];
#pragma unroll
        for (int k = 0; k < 4; ++k) e4[k] = epack[p + k];
        ushort2 vv[4];
        ushort_t sp[4];
#pragma unroll
        for (int k = 0; k < 4; ++k) {
            vv[k] = eb2[(e4[k] >> 16) * 64 + lane];
            sp[k] = x8r[(e4[k] & 0xFFFF) * 64 + lane];
        }
#pragma unroll
        for (int k = 0; k < 4; ++k) {
            float sx = __builtin_amdgcn_cvt_f32_fp8((int)sp[k], 0);
            float sy = __builtin_amdgcn_cvt_f32_fp8((int)sp[k], 1);
            ax += fmaxf(b2f(vv[k].x) + sx, 0.f);
            ay += fmaxf(b2f(vv[k].y) + sy, 0.f);
        }
        p += 4;
    }
    for (; p < p1; ++p) {
        int er = epack[p];
        ushort2 ev = eb2[(er >> 16) * 64 + lane];
        ushort_t sv = x8r[(er & 0xFFFF) * 64 + lane];
        ax += fmaxf(b2f(ev.x) + __builtin_amdgcn_cvt_f32_fp8((int)sv, 0), 0.f);
        ay += fmaxf(b2f(ev.y) + __builtin_amdgcn_cvt_f32_fp8((int)sv, 1), 0.f);
    }
    ushort2 o;
    o.x = f2b(ax);
    o.y = f2b(ay);
    ((ushort2*)h16)[n * 64 + lane] = o;
}

// Fused MLP on MFMA: 32 nodes per block, 256 threads. Epilogue additionally
// emits the FP8 mirror of xout (staged in aS LDS, then coalesced int4 stores).
__global__ void __launch_bounds__(256)
k_mlp_mfma(const ushort_t* __restrict__ h16, const ushort_t* __restrict__ W1P,
           const ushort_t* __restrict__ W2P, const float* __restrict__ b1,
           const float* __restrict__ g1, const float* __restrict__ bt1,
           const float* __restrict__ m1, const float* __restrict__ v1,
           const float* __restrict__ b2_, const float* __restrict__ gO,
           const float* __restrict__ btO, const float* __restrict__ mO,
           const float* __restrict__ vO, int relu, ushort_t* __restrict__ xout,
           uchar_t* __restrict__ x8out) {
    __shared__ ushort_t aS[32 * 136];   // 32 rows x 128 (pad +8); reused as fp8 stage
    __shared__ ushort_t mid[32 * 264];  // 32 rows x 256 (pad +8)
    int t = threadIdx.x;
    int wave = t >> 6, lane = t & 63;
    int row0 = blockIdx.x * 32;
    int lrow = lane & 15, quad = lane >> 4;

#pragma unroll
    for (int ps = 0; ps < 2; ++ps) {
        int idx = ps * 256 + t;
        int r = idx >> 4, c = (idx & 15) * 8;
        *(short8*)&aS[r * 136 + c] = *(const short8*)&h16[(row0 + r) * DD + c];
    }
    __syncthreads();

    f32x4 acc1[2][4];
#pragma unroll
    for (int rt = 0; rt < 2; ++rt)
#pragma unroll
        for (int i = 0; i < 4; ++i) acc1[rt][i] = (f32x4){0.f, 0.f, 0.f, 0.f};
#pragma unroll
    for (int kk = 0; kk < 4; ++kk) {
        short8 af0 = *(const short8*)&aS[lrow * 136 + kk * 32 + quad * 8];
        short8 af1 = *(const short8*)&aS[(16 + lrow) * 136 + kk * 32 + quad * 8];
#pragma unroll
        for (int i = 0; i < 4; ++i) {
            int nt = wave * 4 + i;
            short8 bf = *(const short8*)&W1P[((nt * 4 + kk) * 64 + lane) * 8];
            acc1[0][i] = __builtin_amdgcn_mfma_f32_16x16x32_bf16(af0, bf, acc1[0][i], 0, 0, 0);
            acc1[1][i] = __builtin_amdgcn_mfma_f32_16x16x32_bf16(af1, bf, acc1[1][i], 0, 0, 0);
        }
    }
    __syncthreads();  // aS reads done; safe to reuse as fp8 stage
#pragma unroll
    for (int i = 0; i < 4; ++i) {
        int col = (wave * 4 + i) * 16 + lrow;
        float s1 = g1[col] * rsqrtf(v1[col] + 1e-5f);
        float sh = bt1[col] - (m1[col] - b1[col]) * s1;
#pragma unroll
        for (int rt = 0; rt < 2; ++rt)
#pragma unroll
            for (int r = 0; r < 4; ++r) {
                int row = rt * 16 + quad * 4 + r;
                float o = acc1[rt][i][r] * s1 + sh;
                mid[row * 264 + col] = f2b(fmaxf(o, 0.f));
            }
    }
    __syncthreads();

    f32x4 acc2[2][2];
#pragma unroll
    for (int rt = 0; rt < 2; ++rt)
#pragma unroll
        for (int i = 0; i < 2; ++i) acc2[rt][i] = (f32x4){0.f, 0.f, 0.f, 0.f};
#pragma unroll
    for (int kk = 0; kk < 8; ++kk) {
        short8 af0 = *(const short8*)&mid[lrow * 264 + kk * 32 + quad * 8];
        short8 af1 = *(const short8*)&mid[(16 + lrow) * 264 + kk * 32 + quad * 8];
#pragma unroll
        for (int i = 0; i < 2; ++i) {
            int nt = wave * 2 + i;
            short8 bf = *(const short8*)&W2P[((nt * 8 + kk) * 64 + lane) * 8];
            acc2[0][i] = __builtin_amdgcn_mfma_f32_16x16x32_bf16(af0, bf, acc2[0][i], 0, 0, 0);
            acc2[1][i] = __builtin_amdgcn_mfma_f32_16x16x32_bf16(af1, bf, acc2[1][i], 0, 0, 0);
        }
    }
    uchar_t* s8 = (uchar_t*)aS;  // 32*128 = 4096 B stage
#pragma unroll
    for (int i = 0; i < 2; ++i) {
        int col = (wave * 2 + i) * 16 + lrow;
        float s = gO[col] * rsqrtf(vO[col] + 1e-5f);
        float sh = btO[col] - (mO[col] - b2_[col]) * s;
#pragma unroll
        for (int rt = 0; rt < 2; ++rt)
#pragma unroll
            for (int r = 0; r < 4; ++r) {
                int row = rt * 16 + quad * 4 + r;
                float o = acc2[rt][i][r] * s + sh;
                if (relu) o = fmaxf(o, 0.f);
                xout[(row0 + row) * DD + col] = f2b(o);
                s8[row * DD + col] = f2p8(o);
            }
    }
    __syncthreads();
    ((int4*)(x8out + (size_t)row0 * DD))[t] = ((const int4*)s8)[t];
}

// Fused pool+head: block g reduces its node range, then computes out[g].
__global__ void k_poolhead(const ushort_t* __restrict__ x16,
                           const int* __restrict__ batch,
                           const float* __restrict__ Wp, const float* __restrict__ bp,
                           float* __restrict__ out) {
    int g = blockIdx.x, d = threadIdx.x;  // 128 threads
    int lo = 0, hi = NN;
    while (lo < hi) { int m = (lo + hi) >> 1; if (batch[m] < g) lo = m + 1; else hi = m; }
    int start = lo;
    hi = NN;
    while (lo < hi) { int m = (lo + hi) >> 1; if (batch[m] < g + 1) lo = m + 1; else hi = m; }
    int end = lo;
    float s = 0.f;
    for (int n = start; n < end; ++n) s += b2f(x16[n * DD + d]);
    float c = fmaxf((float)(end - start), 1.f);
    __shared__ float p[DD];
    p[d] = s / c;
    __syncthreads();
    if (d < NT) {
        float acc = bp[d];
#pragma unroll 8
        for (int k = 0; k < DD; ++k) acc = fmaf(p[k], Wp[k * NT + d], acc);
        out[g * NT + d] = acc;
    }
}

extern "C" void kernel_launch(void* const* d_in, const int* in_sizes, int n_in,
                              void* d_out, int out_size, void* d_ws, size_t ws_size,
                              hipStream_t stream) {
    const int* x_atom = (const int*)d_in[0];
    const int* edge_index = (const int*)d_in[1];
    const int* edge_attr = (const int*)d_in[2];
    const int* batch = (const int*)d_in[3];
    const float* atom_emb = (const float*)d_in[4];
    const float* bond_emb = (const float*)d_in[5];
    const float* eps = (const float*)d_in[6];
    const float* W1 = (const float*)d_in[7];
    const float* b1 = (const float*)d_in[8];
    const float* g1 = (const float*)d_in[9];
    const float* bt1 = (const float*)d_in[10];
    const float* m1 = (const float*)d_in[11];
    const float* v1 = (const float*)d_in[12];
    const float* W2 = (const float*)d_in[13];
    const float* b2 = (const float*)d_in[14];
    const float* gO = (const float*)d_in[15];
    const float* btO = (const float*)d_in[16];
    const float* mO = (const float*)d_in[17];
    const float* vO = (const float*)d_in[18];
    const float* Wp = (const float*)d_in[19];
    const float* bp = (const float*)d_in[20];

    ushort_t* x16a = (ushort_t*)d_ws;        // N*D bf16
    ushort_t* x16b = x16a + NN * DD;         // N*D bf16
    ushort_t* h16 = x16b + NN * DD;          // N*D bf16
    ushort_t* W1P = h16 + NN * DD;           // NL*32768 bf16
    ushort_t* W2P = W1P + NL * 32768;        // NL*32768 bf16
    ushort_t* ebsum16 = W2P + NL * 32768;    // NL*512*128 bf16
    uchar_t* x8a = (uchar_t*)(ebsum16 + NL * 65536);  // N*D fp8
    uchar_t* x8b = x8a + NN * DD;            // N*D fp8
    int* off = (int*)(x8b + NN * DD);        // 40064
    int* gcnt = off + 40064;                 // 80 (bucket counts)
    int* gbk = gcnt + 80;                    // 80 (bucket cursors)
    int* bbase = gbk + 80;                   // 128 (needs 81)
    int* epack = bbase + 128;                // NE int (packed src|code<<16)
    int2* ebuf = (int2*)(epack + NE);        // NE int2

    hipMemsetAsync(gcnt, 0, 160 * sizeof(int), stream);

    k_setup<<<4405, 256, 0, stream>>>(W1, W2, bond_emb, x_atom, atom_emb,
                                      edge_index, W1P, W2P, ebsum16, x16a, x8a, gcnt);
    k_bscan<<<1, 128, 0, stream>>>(gcnt, bbase);
    k_bucket<<<NE / 1024, 256, 0, stream>>>(edge_index, edge_attr, bbase, gbk, ebuf);
    k_csr<<<NB, 256, 0, stream>>>(ebuf, bbase, off, epack);

    for (int i = 0; i < NL; ++i) {
        ushort_t* xin = (i & 1) ? x16b : x16a;
        ushort_t* xout = (i & 1) ? x16a : x16b;
        uchar_t* x8in = (i & 1) ? x8b : x8a;
        uchar_t* x8out = (i & 1) ? x8a : x8b;
        k_gather<<<NN / 4, 256, 0, stream>>>(xin, x8in, off, epack,
                                             ebsum16 + i * 65536, eps, i, h16);
        k_mlp_mfma<<<NN / 32, 256, 0, stream>>>(
            h16, W1P + (size_t)i * 32768, W2P + (size_t)i * 32768, b1 + i * 256,
            g1 + i * 256, bt1 + i * 256, m1 + i * 256, v1 + i * 256, b2 + i * DD,
            gO + i * DD, btO + i * DD, mO + i * DD, vO + i * DD,
            (i < NL - 1) ? 1 : 0, xout, x8out);
    }
    k_poolhead<<<NG, DD, 0, stream>>>(x16b, batch, Wp, bp, (float*)d_out);
}

// Round 10
// 382.112 us; speedup vs baseline: 1.1028x; 1.0028x over previous
//
#include <hip/hip_runtime.h>
#include <hip/hip_bf16.h>

#define NN 40000
#define NE 640000
#define NG 2048
#define DD 128
#define NT 10
#define NL 5
#define NB 80  // dst buckets of 512 nodes

typedef __attribute__((ext_vector_type(8))) short short8;
typedef __attribute__((ext_vector_type(8))) float f32x8;
typedef __attribute__((ext_vector_type(4))) float f32x4;
typedef unsigned short ushort_t;
typedef unsigned char uchar_t;

static __device__ __forceinline__ ushort_t f2b(float f) {
    return __bfloat16_as_ushort(__float2bfloat16(f));
}
static __device__ __forceinline__ float b2f(ushort_t u) {
    return __bfloat162float(__ushort_as_bfloat16(u));
}
static __device__ __forceinline__ uchar_t f2p8(float f) {
    return (uchar_t)(__builtin_amdgcn_cvt_pk_fp8_f32(f, 0.f, 0, false) & 0xFF);
}

// ------- fused setup: tables + atom-encode + BUCKET count (80 bins) --------
__global__ void __launch_bounds__(256)
k_setup(const float* __restrict__ W1, const float* __restrict__ W2,
        const float* __restrict__ bemb, const int* __restrict__ xa,
        const float* __restrict__ aemb, const int* __restrict__ ei,
        ushort_t* __restrict__ W1P, ushort_t* __restrict__ W2P,
        ushort_t* __restrict__ ebsum16, ushort_t* __restrict__ x16,
        uchar_t* __restrict__ x8, int* __restrict__ gcnt) {
    int b = blockIdx.x, t = threadIdx.x;
    if (b < 1280) {
        int tid = b * 256 + t;  // < NL*65536
        int layer = tid >> 16;
        int r = tid & 65535;
        int half = r >> 15;
        int q = r & 32767;
        int j = q & 7;
        int lane = (q >> 3) & 63;
        if (half == 0) {
            int kk = (q >> 9) & 3;
            int nt = q >> 11;
            int n = nt * 16 + (lane & 15);
            int k = kk * 32 + (lane >> 4) * 8 + j;
            W1P[layer * 32768 + q] = f2b(W1[(layer * DD + k) * 256 + n]);
        } else {
            int kk = (q >> 9) & 7;
            int nt = q >> 12;
            int n = nt * 16 + (lane & 15);
            int k = kk * 32 + (lane >> 4) * 8 + j;
            W2P[layer * 32768 + q] = f2b(W2[(layer * 256 + k) * DD + n]);
        }
        int d = tid & 127;
        int c = (tid >> 7) & 511;
        const float* bl = bemb + (size_t)layer * 3 * 8 * DD;
        ebsum16[tid] = f2b(bl[(c & 7) * DD + d] + bl[(8 + ((c >> 3) & 7)) * DD + d] +
                           bl[(16 + (c >> 6)) * DD + d]);
    } else if (b < 3780) {
        // atom-encode: 16 nodes/block, thread = (node_local = t>>4, dcol = t&15)
        int bb = b - 1280;
        __shared__ int idxS[144];
        if (t < 144) idxS[t] = xa[bb * 144 + t];
        __syncthreads();
        int nl = t >> 4, dcol = t & 15;
        int n = bb * 16 + nl;
        float acc[8];
#pragma unroll
        for (int k = 0; k < 8; ++k) acc[k] = 0.f;
#pragma unroll
        for (int f = 0; f < 9; ++f) {
            const f32x8 v = *(const f32x8*)&aemb[(f * 64 + idxS[nl * 9 + f]) * DD + dcol * 8];
#pragma unroll
            for (int k = 0; k < 8; ++k) acc[k] += v[k];
        }
        short8 o16;
#pragma unroll
        for (int k = 0; k < 8; ++k) o16[k] = (short)f2b(acc[k]);
        *(short8*)&x16[(size_t)n * DD + dcol * 8] = o16;
        unsigned int lo = 0, hi = 0;
        lo = __builtin_amdgcn_cvt_pk_fp8_f32(acc[0], acc[1], lo, false);
        lo = __builtin_amdgcn_cvt_pk_fp8_f32(acc[2], acc[3], lo, true);
        hi = __builtin_amdgcn_cvt_pk_fp8_f32(acc[4], acc[5], hi, false);
        hi = __builtin_amdgcn_cvt_pk_fp8_f32(acc[6], acc[7], hi, true);
        *(uint2*)&x8[(size_t)n * DD + dcol * 8] = make_uint2(lo, hi);
    } else {
        // bucket count: 1024 edges/block, LDS hist of 80 bins
        __shared__ int hist[NB];
        int e0 = (b - 3780) * 1024;
        if (t < NB) hist[t] = 0;
        __syncthreads();
#pragma unroll
        for (int k = 0; k < 4; ++k) {
            int e = e0 + k * 256 + t;
            atomicAdd(&hist[ei[NE + e] >> 9], 1);
        }
        __syncthreads();
        if (t < NB) atomicAdd(&gcnt[t], hist[t]);
    }
}

// Phase A: bin edges by dst bucket into dense runs of ebuf.
// Bucket bases derived in-block from gcnt (80-entry scan) - no k_bscan.
__global__ void __launch_bounds__(256)
k_bucket(const int* __restrict__ ei, const int* __restrict__ ea,
         const int* __restrict__ gcnt, int* __restrict__ gbk,
         int2* __restrict__ ebuf) {
    __shared__ int hist[NB];
    __shared__ int sbase[NB];
    __shared__ int sB[128];
    __shared__ int exS[NB];
    int t = threadIdx.x;
    if (t < NB) hist[t] = 0;
    int v0 = 0;
    if (t < 128) { v0 = (t < NB) ? gcnt[t] : 0; sB[t] = v0; }
    __syncthreads();
    for (int d = 1; d < 128; d <<= 1) {
        int add = (t < 128 && t >= d) ? sB[t - d] : 0;
        __syncthreads();
        if (t < 128) sB[t] += add;
        __syncthreads();
    }
    if (t < NB) exS[t] = sB[t] - v0;
    __syncthreads();
    int e0 = blockIdx.x * 1024;
    int rank[4], buck[4], rec[4], dstv[4];
#pragma unroll
    for (int k = 0; k < 4; ++k) {
        int e = e0 + k * 256 + t;
        int src = ei[e];
        int dst = ei[NE + e];
        int a0 = ea[e * 3 + 0], a1 = ea[e * 3 + 1], a2 = ea[e * 3 + 2];
        rec[k] = src | ((a0 | (a1 << 3) | (a2 << 6)) << 16);
        dstv[k] = dst;
        int b = dst >> 9;
        buck[k] = b;
        rank[k] = atomicAdd(&hist[b], 1);
    }
    __syncthreads();
    if (t < NB) sbase[t] = atomicAdd(&gbk[t], hist[t]);
    __syncthreads();
#pragma unroll
    for (int k = 0; k < 4; ++k) {
        int b = buck[k];
        int slot = exS[b] + sbase[b] + rank[k];
        ebuf[slot] = make_int2(rec[k], dstv[k]);
    }
}

// Per-bucket CSR + scatter: one block per bucket (512 nodes, ~8000 edges).
// All heavy atomics LDS-scope; bucket base re-derived in-block from gcnt.
__global__ void __launch_bounds__(256)
k_csr(const int2* __restrict__ ebuf, const int* __restrict__ gcnt,
      int* __restrict__ off, int* __restrict__ epack) {
    __shared__ int cnt[512];
    __shared__ int cur[512];
    __shared__ int sc[256];
    __shared__ int sB[128];
    int b = blockIdx.x, t = threadIdx.x;
    int v0 = 0;
    if (t < 128) { v0 = (t < NB) ? gcnt[t] : 0; sB[t] = v0; }
    cnt[t] = 0; cnt[t + 256] = 0;
    cur[t] = 0; cur[t + 256] = 0;
    __syncthreads();
    for (int d = 1; d < 128; d <<= 1) {
        int add = (t < 128 && t >= d) ? sB[t - d] : 0;
        __syncthreads();
        if (t < 128) sB[t] += add;
        __syncthreads();
    }
    int base = sB[b] - gcnt[b];
    int end = base + gcnt[b];
    __syncthreads();
    for (int i = base + t; i < end; i += 256)
        atomicAdd(&cnt[ebuf[i].y & 511], 1);
    __syncthreads();
    int a = cnt[2 * t], c2 = cnt[2 * t + 1];
    sc[t] = a + c2;
    __syncthreads();
    for (int d = 1; d < 256; d <<= 1) {
        int add = (t >= d) ? sc[t - d] : 0;
        __syncthreads();
        sc[t] += add;
        __syncthreads();
    }
    int ex = sc[t] - (a + c2);
    cnt[2 * t] = ex;
    cnt[2 * t + 1] = ex + a;
    int n0 = (b << 9) + 2 * t;
    if (n0 <= NN) off[n0] = base + ex;
    if (n0 + 1 <= NN) off[n0 + 1] = base + ex + a;
    __syncthreads();
    for (int i = base + t; i < end; i += 256) {
        int2 s = ebuf[i];
        int l = s.y & 511;
        int r = atomicAdd(&cur[l], 1);
        epack[base + cnt[l] + r] = s.x;
    }
}

// Gather v4: wave per node; wave splits into 2 half-waves of 32 lanes, each
// half owns one edge (lane = 4 dims). 8-pair pipelined batches -> 16 edges'
// rows in flight per wave (2x round-3). Combine halves via one shfl_xor(32).
__global__ void __launch_bounds__(256)
k_gather(const ushort_t* __restrict__ xin, const uchar_t* __restrict__ x8in,
         const int* __restrict__ off, const int* __restrict__ epack,
         const ushort_t* __restrict__ ebsum16, const float* __restrict__ eps,
         int layer, ushort_t* __restrict__ h16) {
    int t = threadIdx.x;
    int lane = t & 63;
    int half = lane >> 5;    // 0: even edge of pair, 1: odd edge
    int q = lane & 31;       // dims 4q..4q+3
    int n = blockIdx.x * 4 + (t >> 6);
    const ushort4* eb4 = (const ushort4*)ebsum16;   // row = 32 x ushort4
    const uint* xu = (const uint*)x8in;             // row = 32 x uint (4 fp8)
    const ushort4* x4 = (const ushort4*)xin;        // row = 32 x ushort4
    ushort4 xv = x4[(size_t)n * 32 + q];            // self row (both halves load)
    float acc[4];
#pragma unroll
    for (int k = 0; k < 4; ++k) acc[k] = 0.f;
    int p = off[n], p1 = off[n + 1];

    int rec[8], recn[8];
    bool have = (p + 16 <= p1);
    if (have) {
#pragma unroll
        for (int j = 0; j < 8; ++j) rec[j] = epack[p + 2 * j + half];
    }
    while (have) {
        int np = p + 16;
        bool nh = (np + 16 <= p1);
        if (nh) {
#pragma unroll
            for (int j = 0; j < 8; ++j) recn[j] = epack[np + 2 * j + half];
        }
        ushort4 vv[8];
        uint ss[8];
#pragma unroll
        for (int j = 0; j < 8; ++j) {
            vv[j] = eb4[(rec[j] >> 16) * 32 + q];
            ss[j] = xu[(size_t)(rec[j] & 0xFFFF) * 32 + q];
        }
#pragma unroll
        for (int j = 0; j < 8; ++j) {
            acc[0] += fmaxf(b2f(vv[j].x) + __builtin_amdgcn_cvt_f32_fp8((int)ss[j], 0), 0.f);
            acc[1] += fmaxf(b2f(vv[j].y) + __builtin_amdgcn_cvt_f32_fp8((int)ss[j], 1), 0.f);
            acc[2] += fmaxf(b2f(vv[j].z) + __builtin_amdgcn_cvt_f32_fp8((int)ss[j], 2), 0.f);
            acc[3] += fmaxf(b2f(vv[j].w) + __builtin_amdgcn_cvt_f32_fp8((int)ss[j], 3), 0.f);
        }
        p = np;
#pragma unroll
        for (int j = 0; j < 8; ++j) rec[j] = recn[j];
        have = nh;
    }
    if (p + 8 <= p1) {
        int r4[4];
#pragma unroll
        for (int j = 0; j < 4; ++j) r4[j] = epack[p + 2 * j + half];
        ushort4 vv[4];
        uint ss[4];
#pragma unroll
        for (int j = 0; j < 4; ++j) {
            vv[j] = eb4[(r4[j] >> 16) * 32 + q];
            ss[j] = xu[(size_t)(r4[j] & 0xFFFF) * 32 + q];
        }
#pragma unroll
        for (int j = 0; j < 4; ++j) {
            acc[0] += fmaxf(b2f(vv[j].x) + __builtin_amdgcn_cvt_f32_fp8((int)ss[j], 0), 0.f);
            acc[1] += fmaxf(b2f(vv[j].y) + __builtin_amdgcn_cvt_f32_fp8((int)ss[j], 1), 0.f);
            acc[2] += fmaxf(b2f(vv[j].z) + __builtin_amdgcn_cvt_f32_fp8((int)ss[j], 2), 0.f);
            acc[3] += fmaxf(b2f(vv[j].w) + __builtin_amdgcn_cvt_f32_fp8((int)ss[j], 3), 0.f);
        }
        p += 8;
    }
    for (; p < p1; p += 2) {
        int eA = epack[p];
        bool hasB = (p + 1 < p1);
        int eB = hasB ? epack[p + 1] : eA;
        int r = half ? eB : eA;
        bool valid = half ? hasB : true;
        ushort4 v = eb4[(r >> 16) * 32 + q];
        uint s = xu[(size_t)(r & 0xFFFF) * 32 + q];
        if (valid) {
            acc[0] += fmaxf(b2f(v.x) + __builtin_amdgcn_cvt_f32_fp8((int)s, 0), 0.f);
            acc[1] += fmaxf(b2f(v.y) + __builtin_amdgcn_cvt_f32_fp8((int)s, 1), 0.f);
            acc[2] += fmaxf(b2f(v.z) + __builtin_amdgcn_cvt_f32_fp8((int)s, 2), 0.f);
            acc[3] += fmaxf(b2f(v.w) + __builtin_amdgcn_cvt_f32_fp8((int)s, 3), 0.f);
        }
    }
    // combine the two halves
#pragma unroll
    for (int k = 0; k < 4; ++k) acc[k] += __shfl_xor(acc[k], 32, 64);
    if (half == 0) {
        float es = 1.f + eps[layer];
        ushort4 o;
        o.x = f2b(acc[0] + es * b2f(xv.x));
        o.y = f2b(acc[1] + es * b2f(xv.y));
        o.z = f2b(acc[2] + es * b2f(xv.z));
        o.w = f2b(acc[3] + es * b2f(xv.w));
        ((ushort4*)h16)[(size_t)n * 32 + q] = o;
    }
}

// Fused MLP on MFMA: 32 nodes per block, 256 threads. Epilogue additionally
// emits the FP8 mirror of xout (staged in aS LDS, then coalesced int4 stores).
__global__ void __launch_bounds__(256)
k_mlp_mfma(const ushort_t* __restrict__ h16, const ushort_t* __restrict__ W1P,
           const ushort_t* __restrict__ W2P, const float* __restrict__ b1,
           const float* __restrict__ g1, const float* __restrict__ bt1,
           const float* __restrict__ m1, const float* __restrict__ v1,
           const float* __restrict__ b2_, const float* __restrict__ gO,
           const float* __restrict__ btO, const float* __restrict__ mO,
           const float* __restrict__ vO, int relu, ushort_t* __restrict__ xout,
           uchar_t* __restrict__ x8out) {
    __shared__ ushort_t aS[32 * 136];   // 32 rows x 128 (pad +8); reused as fp8 stage
    __shared__ ushort_t mid[32 * 264];  // 32 rows x 256 (pad +8)
    int t = threadIdx.x;
    int wave = t >> 6, lane = t & 63;
    int row0 = blockIdx.x * 32;
    int lrow = lane & 15, quad = lane >> 4;

#pragma unroll
    for (int ps = 0; ps < 2; ++ps) {
        int idx = ps * 256 + t;
        int r = idx >> 4, c = (idx & 15) * 8;
        *(short8*)&aS[r * 136 + c] = *(const short8*)&h16[(row0 + r) * DD + c];
    }
    __syncthreads();

    f32x4 acc1[2][4];
#pragma unroll
    for (int rt = 0; rt < 2; ++rt)
#pragma unroll
        for (int i = 0; i < 4; ++i) acc1[rt][i] = (f32x4){0.f, 0.f, 0.f, 0.f};
#pragma unroll
    for (int kk = 0; kk < 4; ++kk) {
        short8 af0 = *(const short8*)&aS[lrow * 136 + kk * 32 + quad * 8];
        short8 af1 = *(const short8*)&aS[(16 + lrow) * 136 + kk * 32 + quad * 8];
#pragma unroll
        for (int i = 0; i < 4; ++i) {
            int nt = wave * 4 + i;
            short8 bf = *(const short8*)&W1P[((nt * 4 + kk) * 64 + lane) * 8];
            acc1[0][i] = __builtin_amdgcn_mfma_f32_16x16x32_bf16(af0, bf, acc1[0][i], 0, 0, 0);
            acc1[1][i] = __builtin_amdgcn_mfma_f32_16x16x32_bf16(af1, bf, acc1[1][i], 0, 0, 0);
        }
    }
    __syncthreads();  // aS reads done; safe to reuse as fp8 stage
#pragma unroll
    for (int i = 0; i < 4; ++i) {
        int col = (wave * 4 + i) * 16 + lrow;
        float s1 = g1[col] * rsqrtf(v1[col] + 1e-5f);
        float sh = bt1[col] - (m1[col] - b1[col]) * s1;
#pragma unroll
        for (int rt = 0; rt < 2; ++rt)
#pragma unroll
            for (int r = 0; r < 4; ++r) {
                int row = rt * 16 + quad * 4 + r;
                float o = acc1[rt][i][r] * s1 + sh;
                mid[row * 264 + col] = f2b(fmaxf(o, 0.f));
            }
    }
    __syncthreads();

    f32x4 acc2[2][2];
#pragma unroll
    for (int rt = 0; rt < 2; ++rt)
#pragma unroll
        for (int i = 0; i < 2; ++i) acc2[rt][i] = (f32x4){0.f, 0.f, 0.f, 0.f};
#pragma unroll
    for (int kk = 0; kk < 8; ++kk) {
        short8 af0 = *(const short8*)&mid[lrow * 264 + kk * 32 + quad * 8];
        short8 af1 = *(const short8*)&mid[(16 + lrow) * 264 + kk * 32 + quad * 8];
#pragma unroll
        for (int i = 0; i < 2; ++i) {
            int nt = wave * 2 + i;
            short8 bf = *(const short8*)&W2P[((nt * 8 + kk) * 64 + lane) * 8];
            acc2[0][i] = __builtin_amdgcn_mfma_f32_16x16x32_bf16(af0, bf, acc2[0][i], 0, 0, 0);
            acc2[1][i] = __builtin_amdgcn_mfma_f32_16x16x32_bf16(af1, bf, acc2[1][i], 0, 0, 0);
        }
    }
    uchar_t* s8 = (uchar_t*)aS;  // 32*128 = 4096 B stage
#pragma unroll
    for (int i = 0; i < 2; ++i) {
        int col = (wave * 2 + i) * 16 + lrow;
        float s = gO[col] * rsqrtf(vO[col] + 1e-5f);
        float sh = btO[col] - (mO[col] - b2_[col]) * s;
#pragma unroll
        for (int rt = 0; rt < 2; ++rt)
#pragma unroll
            for (int r = 0; r < 4; ++r) {
                int row = rt * 16 + quad * 4 + r;
                float o = acc2[rt][i][r] * s + sh;
                if (relu) o = fmaxf(o, 0.f);
                xout[(row0 + row) * DD + col] = f2b(o);
                s8[row * DD + col] = f2p8(o);
            }
    }
    __syncthreads();
    ((int4*)(x8out + (size_t)row0 * DD))[t] = ((const int4*)s8)[t];
}

// Fused pool+head: 256 threads = 4 row-stripes x 64 dim-pairs (ushort2).
__global__ void k_poolhead(const ushort_t* __restrict__ x16,
                           const int* __restrict__ batch,
                           const float* __restrict__ Wp, const float* __restrict__ bp,
                           float* __restrict__ out) {
    int g = blockIdx.x, t = threadIdx.x;  // 256 threads
    int j = t >> 6, l = t & 63;
    int lo = 0, hi = NN;
    while (lo < hi) { int m = (lo + hi) >> 1; if (batch[m] < g) lo = m + 1; else hi = m; }
    int start = lo;
    hi = NN;
    while (lo < hi) { int m = (lo + hi) >> 1; if (batch[m] < g + 1) lo = m + 1; else hi = m; }
    int end = lo;
    const ushort2* x2 = (const ushort2*)x16;
    float sx = 0.f, sy = 0.f;
    for (int n = start + j; n < end; n += 4) {
        ushort2 v = x2[(size_t)n * 64 + l];
        sx += b2f(v.x);
        sy += b2f(v.y);
    }
    __shared__ float pp[4][DD];
    pp[j][2 * l] = sx;
    pp[j][2 * l + 1] = sy;
    __syncthreads();
    __shared__ float pfin[DD];
    if (t < DD) {
        float c = fmaxf((float)(end - start), 1.f);
        pfin[t] = (pp[0][t] + pp[1][t] + pp[2][t] + pp[3][t]) / c;
    }
    __syncthreads();
    if (t < NT) {
        float acc = bp[t];
#pragma unroll 8
        for (int k = 0; k < DD; ++k) acc = fmaf(pfin[k], Wp[k * NT + t], acc);
        out[g * NT + t] = acc;
    }
}

extern "C" void kernel_launch(void* const* d_in, const int* in_sizes, int n_in,
                              void* d_out, int out_size, void* d_ws, size_t ws_size,
                              hipStream_t stream) {
    const int* x_atom = (const int*)d_in[0];
    const int* edge_index = (const int*)d_in[1];
    const int* edge_attr = (const int*)d_in[2];
    const int* batch = (const int*)d_in[3];
    const float* atom_emb = (const float*)d_in[4];
    const float* bond_emb = (const float*)d_in[5];
    const float* eps = (const float*)d_in[6];
    const float* W1 = (const float*)d_in[7];
    const float* b1 = (const float*)d_in[8];
    const float* g1 = (const float*)d_in[9];
    const float* bt1 = (const float*)d_in[10];
    const float* m1 = (const float*)d_in[11];
    const float* v1 = (const float*)d_in[12];
    const float* W2 = (const float*)d_in[13];
    const float* b2 = (const float*)d_in[14];
    const float* gO = (const float*)d_in[15];
    const float* btO = (const float*)d_in[16];
    const float* mO = (const float*)d_in[17];
    const float* vO = (const float*)d_in[18];
    const float* Wp = (const float*)d_in[19];
    const float* bp = (const float*)d_in[20];

    ushort_t* x16a = (ushort_t*)d_ws;        // N*D bf16
    ushort_t* x16b = x16a + NN * DD;         // N*D bf16
    ushort_t* h16 = x16b + NN * DD;          // N*D bf16
    ushort_t* W1P = h16 + NN * DD;           // NL*32768 bf16
    ushort_t* W2P = W1P + NL * 32768;        // NL*32768 bf16
    ushort_t* ebsum16 = W2P + NL * 32768;    // NL*512*128 bf16
    uchar_t* x8a = (uchar_t*)(ebsum16 + NL * 65536);  // N*D fp8
    uchar_t* x8b = x8a + NN * DD;            // N*D fp8
    int* off = (int*)(x8b + NN * DD);        // 40064
    int* gcnt = off + 40064;                 // 80 (bucket counts)
    int* gbk = gcnt + 80;                    // 80 (bucket cursors)
    int* epack = gbk + 80;                   // NE int (packed src|code<<16)
    int2* ebuf = (int2*)(epack + NE);        // NE int2

    hipMemsetAsync(gcnt, 0, 160 * sizeof(int), stream);

    k_setup<<<4405, 256, 0, stream>>>(W1, W2, bond_emb, x_atom, atom_emb,
                                      edge_index, W1P, W2P, ebsum16, x16a, x8a, gcnt);
    k_bucket<<<NE / 1024, 256, 0, stream>>>(edge_index, edge_attr, gcnt, gbk, ebuf);
    k_csr<<<NB, 256, 0, stream>>>(ebuf, gcnt, off, epack);

    for (int i = 0; i < NL; ++i) {
        ushort_t* xin = (i & 1) ? x16b : x16a;
        ushort_t* xout = (i & 1) ? x16a : x16b;
        uchar_t* x8in = (i & 1) ? x8b : x8a;
        uchar_t* x8out = (i & 1) ? x8a : x8b;
        k_gather<<<NN / 4, 256, 0, stream>>>(xin, x8in, off, epack,
                                             ebsum16 + i * 65536, eps, i, h16);
        k_mlp_mfma<<<NN / 32, 256, 0, stream>>>(
            h16, W1P + (size_t)i * 32768, W2P + (size_t)i * 32768, b1 + i * 256,
            g1 + i * 256, bt1 + i * 256, m1 + i * 256, v1 + i * 256, b2 + i * DD,
            gO + i * DD, btO + i * DD, mO + i * DD, vO + i * DD,
            (i < NL - 1) ? 1 : 0, xout, x8out);
    }
    k_poolhead<<<NG, 256, 0, stream>>>(x16b, batch, Wp, bp, (float*)d_out);
}